// Round 6
// baseline (1277.265 us; speedup 1.0000x reference)
//
#include <hip/hip_runtime.h>
#include <hip/hip_fp16.h>
#include <cstddef>

#define BB    4
#define NN    10000
#define EE    160000
#define BN    40000      // BB*NN
#define HISTC 8
#define PREDC 12
#define TSTEP 20         // HIST+PRED
#define FEX   8
#define HIDC  64
#define EHID  32
#define EOUTC 30
#define GOUTC 13
#define GINC  22         // GOUTC + 9

typedef float v2f __attribute__((ext_vector_type(2)));
typedef _Float16 v2h __attribute__((ext_vector_type(2)));

struct alignas(16) WPack {      // 128 B: one layer-2 output channel
    __half2 w[16];   // w2 row (32 halves)
    float   nw[14];  // folded n_w row (13 + pad)
    float   b2;
    float   pad;
};

__device__ __forceinline__ float fast_rcp(float x) { return __builtin_amdgcn_rcpf(x); }
__device__ __forceinline__ float sigm(float x) {
    return fast_rcp(1.0f + __expf(-x));
}
__device__ __forceinline__ v2f sigm2(v2f x) {
    v2f r; r.x = sigm(x.x); r.y = sigm(x.y); return r;
}
__device__ __forceinline__ float tanh_fast(float x) {
    x = fminf(fmaxf(x, -15.0f), 15.0f);
    float e = __expf(2.0f * x);
    return (e - 1.0f) * fast_rcp(e + 1.0f);
}

__device__ __forceinline__ float dot2(__half2 a, __half2 b, float c) {
#if __has_builtin(__builtin_amdgcn_fdot2)
    union { __half2 h; v2h v; } ua, ub;
    ua.h = a; ub.h = b;
    return __builtin_amdgcn_fdot2(ua.v, ub.v, c, false);
#else
    float2 fa = __half22float2(a), fb = __half22float2(b);
    return c + fa.x * fb.x + fa.y * fb.y;
#endif
}

// ---------------- edge_attr stats ---------------------------------------------
__global__ __launch_bounds__(256) void stats1_kernel(const float* __restrict__ ea,
                                                     double* __restrict__ part) {
    __shared__ double sm[256][4];
    int tid = threadIdx.x;
    double s0 = 0, s1 = 0, q0 = 0, q1 = 0;
    for (int e = blockIdx.x * 256 + tid; e < EE; e += 256 * 256) {
        float2 v = reinterpret_cast<const float2*>(ea)[e];
        double v0 = (double)v.x, v1 = (double)v.y;
        s0 += v0; q0 += v0 * v0;
        s1 += v1; q1 += v1 * v1;
    }
    sm[tid][0] = s0; sm[tid][1] = s1; sm[tid][2] = q0; sm[tid][3] = q1;
    __syncthreads();
    for (int off = 128; off > 0; off >>= 1) {
        if (tid < off)
            for (int k = 0; k < 4; k++) sm[tid][k] += sm[tid + off][k];
        __syncthreads();
    }
    if (tid == 0) {
        part[blockIdx.x * 4 + 0] = sm[0][0];
        part[blockIdx.x * 4 + 1] = sm[0][1];
        part[blockIdx.x * 4 + 2] = sm[0][2];
        part[blockIdx.x * 4 + 3] = sm[0][3];
    }
}

__global__ __launch_bounds__(256) void stats2_kernel(const double* __restrict__ part,
                                                     float* __restrict__ stats) {
    __shared__ double sm[256][4];
    int tid = threadIdx.x;
    sm[tid][0] = part[tid * 4 + 0];
    sm[tid][1] = part[tid * 4 + 1];
    sm[tid][2] = part[tid * 4 + 2];
    sm[tid][3] = part[tid * 4 + 3];
    __syncthreads();
    for (int off = 128; off > 0; off >>= 1) {
        if (tid < off)
            for (int k = 0; k < 4; k++) sm[tid][k] += sm[tid + off][k];
        __syncthreads();
    }
    if (tid == 0) {
        double m0 = sm[0][0] / EE, m1 = sm[0][1] / EE;
        double v0 = (sm[0][2] - sm[0][0] * sm[0][0] / EE) / (double)(EE - 1);
        double v1 = (sm[0][3] - sm[0][1] * sm[0][1] / EE) / (double)(EE - 1);
        float sd0 = fmaxf((float)sqrt(v0 > 0 ? v0 : 0.0), 1e-6f);
        float sd1 = fmaxf((float)sqrt(v1 > 0 ? v1 : 0.0), 1e-6f);
        stats[0] = (float)m0; stats[1] = (float)m1;
        stats[2] = 1.0f / sd0; stats[3] = 1.0f / sd1;
    }
}

// ---------------- per-edge precompute + degree histogram (fused) --------------
__global__ __launch_bounds__(256) void edgepre_kernel(
    const float* __restrict__ ea, const float* __restrict__ stats,
    const int* __restrict__ eidx,
    int* __restrict__ deg_t, int* __restrict__ deg_s,
    float4* __restrict__ epre4)
{
    int e = blockIdx.x * 256 + threadIdx.x;
    if (e >= EE) return;
    float2 v = reinterpret_cast<const float2*>(ea)[e];
    float4 r;
    r.x = (v.x - stats[0]) * stats[2];
    r.y = (v.y - stats[1]) * stats[3];
    r.z = 1.0f / fmaxf(v.x, 1e-3f);
    r.w = v.y;
    epre4[e] = r;
    atomicAdd(&deg_s[eidx[e]], 1);
    atomicAdd(&deg_t[eidx[EE + e]], 1);
}

// ---------------- weight conversion + WPack build (once per call) -------------
__global__ __launch_bounds__(256) void cvtw_kernel(
    const float* __restrict__ wi, const float* __restrict__ wh,
    const float* __restrict__ ew2, const float* __restrict__ eb2,
    const float* __restrict__ nw,
    __half* __restrict__ wi_h, __half* __restrict__ wh_h,
    WPack* __restrict__ wpack)
{
    int i = blockIdx.x * 256 + threadIdx.x;
    if (i < 192 * GINC) wi_h[i] = __float2half(wi[i]);
    if (i < 192 * HIDC) wh_h[i] = __float2half(wh[i]);
    if (i < EOUTC) {
        WPack wp;
        #pragma unroll
        for (int q = 0; q < 16; q++)
            wp.w[q] = __floats2half2_rn(ew2[(2 * q) * EOUTC + i],
                                        ew2[(2 * q + 1) * EOUTC + i]);
        #pragma unroll
        for (int j = 0; j < GOUTC; j++) wp.nw[j] = nw[i * GOUTC + j];
        wp.nw[13] = 0.f;
        wp.b2 = eb2[i];
        wp.pad = 0.f;
        wpack[i] = wp;
    }
}

// ---------------- xn init -----------------------------------------------------
__global__ void initxn_kernel(const float* __restrict__ pm, float* __restrict__ xn) {
    int i = blockIdx.x * 256 + threadIdx.x;
    if (i >= BN) return;
    int b = i / NN, n = i - b * NN;
    xn[i] = pm[(b * HISTC + (HISTC - 1)) * NN + n];
}

// ---------------- CSR scan ----------------------------------------------------
__global__ __launch_bounds__(1024) void scan_kernel(
    const int* __restrict__ deg_t, const int* __restrict__ deg_s,
    int* __restrict__ off_t, int* __restrict__ off_s,
    int* __restrict__ cnt_t, int* __restrict__ cnt_s)
{
    __shared__ int pt[1024], ps[1024];
    int tid = threadIdx.x;
    int base = tid * 10;
    int st = 0, ss = 0;
    for (int k = 0; k < 10; k++) {
        int i = base + k;
        if (i < NN) { st += deg_t[i]; ss += deg_s[i]; }
    }
    pt[tid] = st; ps[tid] = ss;
    __syncthreads();
    for (int off = 1; off < 1024; off <<= 1) {
        int vt = (tid >= off) ? pt[tid - off] : 0;
        int vs = (tid >= off) ? ps[tid - off] : 0;
        __syncthreads();
        pt[tid] += vt; ps[tid] += vs;
        __syncthreads();
    }
    int ext = (tid == 0) ? 0 : pt[tid - 1];
    int exs = (tid == 0) ? 0 : ps[tid - 1];
    for (int k = 0; k < 10; k++) {
        int i = base + k;
        if (i < NN) {
            off_t[i] = ext; cnt_t[i] = ext;
            off_s[i] = exs; cnt_s[i] = exs;
            ext += deg_t[i]; exs += deg_s[i];
        }
    }
    if (tid == 0) { off_t[NN] = EE; off_s[NN] = EE; }
}

// fill+perm fused: directly scatter eT[slot]={src,tgt,pos_s}, epreT[slot]
__global__ void fillperm_kernel(const int* __restrict__ eidx,
                                const float4* __restrict__ epre4,
                                int* __restrict__ cnt_t, int* __restrict__ cnt_s,
                                int4* __restrict__ eT, float4* __restrict__ epreT)
{
    int e = blockIdx.x * 256 + threadIdx.x;
    if (e >= EE) return;
    int s = eidx[e];
    int g = eidx[EE + e];
    int pt = atomicAdd(&cnt_t[g], 1);
    int ps = atomicAdd(&cnt_s[s], 1);
    int4 r; r.x = s; r.y = g; r.z = ps; r.w = 0;
    eT[pt] = r;
    epreT[pt] = epre4[e];
}

// ---------------- per-step node precompute (t=0 only; tail of node does t>0) --
__global__ __launch_bounds__(256) void pre_kernel(
    const float* __restrict__ xncur, const float* __restrict__ feature, int t,
    const float* __restrict__ ew1,
    const float* __restrict__ wmean, const float* __restrict__ wstd,
    __half* __restrict__ preS, __half* __restrict__ preT,
    float2* __restrict__ wind2)
{
    __shared__ alignas(16) float w1s[18 * EHID];
    for (int i = threadIdx.x; i < 18 * EHID; i += 256) w1s[i] = ew1[i];
    __syncthreads();
    int idx = blockIdx.x * 256 + threadIdx.x;
    if (idx >= BN * 8) return;
    int i = idx >> 3;
    int c = idx & 7;
    int b = i / NN, n = i - b * NN;
    float x[9];
    x[0] = xncur[i];
    {
        const float4* fp = reinterpret_cast<const float4*>(
            feature + (((size_t)b * TSTEP + HISTC + t) * NN + n) * FEX);
        float4 u = fp[0], v = fp[1];
        x[1] = u.x; x[2] = u.y; x[3] = u.z; x[4] = u.w;
        x[5] = v.x; x[6] = v.y; x[7] = v.z; x[8] = v.w;
    }
    float4 aS = {0.f, 0.f, 0.f, 0.f}, aT = {0.f, 0.f, 0.f, 0.f};
    #pragma unroll
    for (int k = 0; k < 9; k++) {
        float4 wS = reinterpret_cast<const float4*>(&w1s[k * EHID])[c];
        float4 wT = reinterpret_cast<const float4*>(&w1s[(9 + k) * EHID])[c];
        aS.x += x[k] * wS.x; aS.y += x[k] * wS.y; aS.z += x[k] * wS.z; aS.w += x[k] * wS.w;
        aT.x += x[k] * wT.x; aT.y += x[k] * wT.y; aT.z += x[k] * wT.z; aT.w += x[k] * wT.w;
    }
    union { uint2 u; __half h[4]; } sv, tv;
    sv.h[0] = __float2half(aS.x); sv.h[1] = __float2half(aS.y);
    sv.h[2] = __float2half(aS.z); sv.h[3] = __float2half(aS.w);
    tv.h[0] = __float2half(aT.x); tv.h[1] = __float2half(aT.y);
    tv.h[2] = __float2half(aT.z); tv.h[3] = __float2half(aT.w);
    reinterpret_cast<uint2*>(preS + (size_t)i * EHID)[c] = sv.u;
    reinterpret_cast<uint2*>(preT + (size_t)i * EHID)[c] = tv.u;
    if (c == 1) {
        float sd0 = fmaxf(wstd[0], 1e-6f), sd1 = fmaxf(wstd[1], 1e-6f);
        float speed = fmaxf(x[7] * sd0 + wmean[0], 0.f);
        float wdir  = (x[8] * sd1 + wmean[1]) * 0.017453292519943295f;
        float2 wv; wv.x = 3.0f * speed; wv.y = wdir;
        wind2[i] = wv;
    }
}

// ---------------- edge MLP, tgt-slot order, 1 batch/thread, grid (625,4) ------
// Round-0 body: scalar (wave-uniform) weight loads, no LDS staging.
__global__ __launch_bounds__(256) void edge_kernel(
    const int4* __restrict__ eT, const float4* __restrict__ epreT,
    const __half* __restrict__ preS, const __half* __restrict__ preT,
    const float2* __restrict__ wind2,
    const float* __restrict__ ew1, const float* __restrict__ eb1,
    const WPack* __restrict__ wpack,
    __half* __restrict__ h3t, __half* __restrict__ h3s)
{
    int i = blockIdx.x * 256 + threadIdx.x;   // slot (EE == 625*256, no tail)
    int b = blockIdx.y;
    int4 et = eT[i];
    int s = et.x, g = et.y, ps = et.z;
    float4 ep = epreT[i];          // {ean0, ean1, 1/dist, direc}

    size_t iS = (size_t)b * NN + s, iT = (size_t)b * NN + g;
    float2 wv2 = wind2[iS];
    float ew = fmaxf(wv2.x * __cosf(fabsf(ep.w - wv2.y)) * ep.z, 0.f);

    union alignas(16) { uint4 u[4]; __half2 h2[16]; } RS, RT;
    {
        const uint4* p;
        p = reinterpret_cast<const uint4*>(preS + iS * EHID);
        RS.u[0] = p[0]; RS.u[1] = p[1]; RS.u[2] = p[2]; RS.u[3] = p[3];
        p = reinterpret_cast<const uint4*>(preT + iT * EHID);
        RT.u[0] = p[0]; RT.u[1] = p[1]; RT.u[2] = p[2]; RT.u[3] = p[3];
    }

    const v2f* W18 = reinterpret_cast<const v2f*>(ew1 + 18 * EHID);
    const v2f* W19 = reinterpret_cast<const v2f*>(ew1 + 19 * EHID);
    const v2f* W20 = reinterpret_cast<const v2f*>(ew1 + 20 * EHID);
    const v2f* B1  = reinterpret_cast<const v2f*>(eb1);
    float ean0 = ep.x, ean1 = ep.y;
    __half2 h1h[16];
    #pragma unroll
    for (int q = 0; q < 16; q++) {
        v2f u = W18[q] * ean0 + W19[q] * ean1 + B1[q] + W20[q] * ew;
        float2 rs = __half22float2(RS.h2[q]);
        float2 rt = __half22float2(RT.h2[q]);
        u.x += rs.x + rt.x;
        u.y += rs.y + rt.y;
        v2f sg = sigm2(u);
        h1h[q] = __floats2half2_rn(sg.x, sg.y);
    }

    v2f h3p[7];
    #pragma unroll
    for (int j = 0; j < 7; j++) { h3p[j].x = 0.f; h3p[j].y = 0.f; }
    for (int o = 0; o < EOUTC; o++) {
        const WPack* W = wpack + o;
        float acc0 = W->b2, acc1 = 0.f;
        #pragma unroll
        for (int q = 0; q < 16; q += 2) {
            acc0 = dot2(h1h[q],     W->w[q],     acc0);
            acc1 = dot2(h1h[q + 1], W->w[q + 1], acc1);
        }
        float h2v = sigm(acc0 + acc1);
        const v2f* nr = reinterpret_cast<const v2f*>(W->nw);
        #pragma unroll
        for (int j = 0; j < 7; j++) h3p[j] += nr[j] * h2v;
    }

    union alignas(16) { uint4 u[2]; __half2 h2[8]; } r;
    #pragma unroll
    for (int j = 0; j < 7; j++) r.h2[j] = __floats2half2_rn(h3p[j].x, h3p[j].y);
    r.h2[7] = __floats2half2_rn(0.f, 0.f);
    {
        __half* oT = h3t + ((size_t)b * EE + i) * 16;     // coalesced
        reinterpret_cast<uint4*>(oT)[0] = r.u[0];
        reinterpret_cast<uint4*>(oT)[1] = r.u[1];
        __half* oS = h3s + ((size_t)b * EE + ps) * 16;    // scattered
        reinterpret_cast<uint4*>(oS)[0] = r.u[0];
        reinterpret_cast<uint4*>(oS)[1] = r.u[1];
    }
}

// ---------------- gather + gnn-out sigmoid -> fp16 xcagg (round-0) ------------
__global__ __launch_bounds__(256) void gather_kernel(
    const __half* __restrict__ h3t, const __half* __restrict__ h3s,
    const int* __restrict__ off_t, const int* __restrict__ off_s,
    const float* __restrict__ nb, const float* __restrict__ xncur,
    __half* __restrict__ xcagg)
{
    int n = (blockIdx.x * 256 + threadIdx.x) >> 6;
    if (n >= NN) return;
    n = __builtin_amdgcn_readfirstlane(n);
    int lane = threadIdx.x & 63;
    int b = lane >> 4, ch = lane & 15;
    const __half* ht = h3t + (size_t)b * EE * 16 + ch;
    const __half* hs = h3s + (size_t)b * EE * 16 + ch;
    float a0 = 0.f, a1 = 0.f, a2 = 0.f, a3 = 0.f;
    {
        int i0 = off_t[n], i1 = off_t[n + 1];
        int i = i0;
        for (; i + 4 <= i1; i += 4) {
            a0 += __half2float(ht[(size_t)(i + 0) * 16]);
            a1 += __half2float(ht[(size_t)(i + 1) * 16]);
            a2 += __half2float(ht[(size_t)(i + 2) * 16]);
            a3 += __half2float(ht[(size_t)(i + 3) * 16]);
        }
        for (; i < i1; i++) a0 += __half2float(ht[(size_t)i * 16]);
    }
    {
        int i0 = off_s[n], i1 = off_s[n + 1];
        int i = i0;
        for (; i + 4 <= i1; i += 4) {
            a0 -= __half2float(hs[(size_t)(i + 0) * 16]);
            a1 -= __half2float(hs[(size_t)(i + 1) * 16]);
            a2 -= __half2float(hs[(size_t)(i + 2) * 16]);
            a3 -= __half2float(hs[(size_t)(i + 3) * 16]);
        }
        for (; i < i1; i++) a0 -= __half2float(hs[(size_t)i * 16]);
    }
    float acc = (a0 + a1) + (a2 + a3);
    float val;
    if (ch < GOUTC) {
        val = sigm(acc + nb[ch]);
    } else if (ch == GOUTC) {
        val = xncur[(size_t)b * NN + n];
    } else {
        val = 0.f;
    }
    xcagg[((size_t)b * NN + n) * 16 + ch] = __float2half(val);
}

// ---------------- node: GRU merged 64-dims/block + fused pre(t+1) tail --------
// 625 blocks x 1024 thr = 10000 waves; j wave-uniform (readfirstlane) ->
// scalar weight loads; hnold staged in LDS; fc finished in-block; then the
// SAME block computes preS/preT/wind2 for step t+1 (tables L2-warm for edge).
__global__ __launch_bounds__(1024, 4) void node_kernel(
    const __half* __restrict__ xcagg, const float* __restrict__ feature, int t,
    const __half* __restrict__ wi_h, const __half* __restrict__ wh_h,
    const float* __restrict__ bi, const float* __restrict__ bh,
    const float* __restrict__ fw, const float* __restrict__ fb,
    const __half2* __restrict__ hnold, __half2* __restrict__ hnnew,
    float* __restrict__ xncur, float* __restrict__ out,
    const float* __restrict__ ew1,
    const float* __restrict__ wmean, const float* __restrict__ wstd,
    __half* __restrict__ preS, __half* __restrict__ preT,
    float2* __restrict__ wind2)
{
    __shared__ __half2 shh[32][65];       // 8320 B, +1 pad -> conflict-free
    __shared__ float xpart[16][64];       // 4096 B
    __shared__ alignas(16) float w1s[18 * EHID];   // 2304 B (for pre tail)
    __shared__ float xnewS[64];
    int tid  = threadIdx.x;
    int lane = tid & 63;
    int wav  = tid >> 6;                  // 16 waves
    int g0   = blockIdx.x * 64;           // 625 blocks, no tail

    // stage hnold for the block's 64 nodes + w1 table for the pre tail
    for (int k = tid; k < 32 * 64; k += 1024) {
        int p = k >> 6, l = k & 63;
        shh[p][l] = hnold[(size_t)p * BN + g0 + l];
    }
    if (tid < 18 * EHID) w1s[tid] = ew1[tid];
    __syncthreads();

    int node = g0 + lane;
    int b = node / NN;
    int n = node - b * NN;

    __half2 xch[11];
    {
        union alignas(16) { uint4 u[2]; __half2 h2[8]; } X;
        const uint4* xp16 = reinterpret_cast<const uint4*>(xcagg + (size_t)node * 16);
        X.u[0] = xp16[0]; X.u[1] = xp16[1];
        #pragma unroll
        for (int p = 0; p < 7; p++) xch[p] = X.h2[p];   // ch 0..13 (incl. xn)
    }
    {
        const float4* fp = reinterpret_cast<const float4*>(
            feature + (((size_t)b * TSTEP + HISTC + t) * NN + n) * FEX);
        float4 u = fp[0], v = fp[1];
        xch[7]  = __floats2half2_rn(u.x, u.y);
        xch[8]  = __floats2half2_rn(u.z, u.w);
        xch[9]  = __floats2half2_rn(v.x, v.y);
        xch[10] = __floats2half2_rn(v.z, v.w);
    }

    __half2 hh[32];
    #pragma unroll
    for (int p = 0; p < 32; p++) hh[p] = shh[p][lane];

    float hnew4[4];
    float xsum = 0.f;
    #pragma unroll
    for (int d = 0; d < 4; d++) {
        int j = __builtin_amdgcn_readfirstlane(wav * 4 + d);
        float ir = bi[j], iz = bi[64 + j], in_ = bi[128 + j];
        const __half2* wr0 = reinterpret_cast<const __half2*>(wi_h + (size_t)j * GINC);
        const __half2* wr1 = reinterpret_cast<const __half2*>(wi_h + (size_t)(64 + j) * GINC);
        const __half2* wr2 = reinterpret_cast<const __half2*>(wi_h + (size_t)(128 + j) * GINC);
        #pragma unroll
        for (int p = 0; p < 11; p++) {
            ir  = dot2(xch[p], wr0[p], ir);
            iz  = dot2(xch[p], wr1[p], iz);
            in_ = dot2(xch[p], wr2[p], in_);
        }
        float hr0 = bh[j], hz0 = bh[64 + j], hn0 = bh[128 + j];
        float hr1 = 0.f, hz1 = 0.f, hn1 = 0.f;
        const __half2* vr0 = reinterpret_cast<const __half2*>(wh_h + (size_t)j * HIDC);
        const __half2* vr1 = reinterpret_cast<const __half2*>(wh_h + (size_t)(64 + j) * HIDC);
        const __half2* vr2 = reinterpret_cast<const __half2*>(wh_h + (size_t)(128 + j) * HIDC);
        #pragma unroll
        for (int p = 0; p < 32; p += 2) {
            hr0 = dot2(hh[p],     vr0[p],     hr0);
            hz0 = dot2(hh[p],     vr1[p],     hz0);
            hn0 = dot2(hh[p],     vr2[p],     hn0);
            hr1 = dot2(hh[p + 1], vr0[p + 1], hr1);
            hz1 = dot2(hh[p + 1], vr1[p + 1], hz1);
            hn1 = dot2(hh[p + 1], vr2[p + 1], hn1);
        }
        float r  = sigm(ir + hr0 + hr1);
        float z  = sigm(iz + hz0 + hz1);
        float nl = tanh_fast(in_ + r * (hn0 + hn1));
        union { __half2 h; __half v[2]; } hold2;
        hold2.h = hh[(wav * 4 + d) >> 1];
        float hold = __half2float(hold2.v[d & 1]);
        float hnew = (1.f - z) * nl + z * hold;
        hnew4[d] = hnew;
        xsum += hnew * fw[j];
    }
    hnnew[(size_t)(wav * 2) * BN + node]     = __floats2half2_rn(hnew4[0], hnew4[1]);
    hnnew[(size_t)(wav * 2 + 1) * BN + node] = __floats2half2_rn(hnew4[2], hnew4[3]);
    xpart[wav][lane] = xsum;
    __syncthreads();
    if (tid < 64) {
        float tot = 0.f;
        #pragma unroll
        for (int w2 = 0; w2 < 16; w2++) tot += xpart[w2][tid];
        int node2 = g0 + tid;
        float xnew = tot + fb[0];
        xncur[node2] = xnew;
        out[(size_t)node2 * PREDC + t] = xnew;
        xnewS[tid] = xnew;
    }
    __syncthreads();

    // ---- fused pre for step t+1 (threads 0..511; r0 pre math verbatim) ----
    if (t + 1 < PREDC && tid < 512) {
        int c  = tid & 7;
        int ln = tid >> 3;                 // 0..63
        int i2 = g0 + ln;
        int b2 = i2 / NN, n2 = i2 - b2 * NN;
        float x[9];
        x[0] = xnewS[ln];
        {
            const float4* fp = reinterpret_cast<const float4*>(
                feature + (((size_t)b2 * TSTEP + HISTC + (t + 1)) * NN + n2) * FEX);
            float4 u = fp[0], v = fp[1];
            x[1] = u.x; x[2] = u.y; x[3] = u.z; x[4] = u.w;
            x[5] = v.x; x[6] = v.y; x[7] = v.z; x[8] = v.w;
        }
        float4 aS = {0.f, 0.f, 0.f, 0.f}, aT = {0.f, 0.f, 0.f, 0.f};
        #pragma unroll
        for (int k = 0; k < 9; k++) {
            float4 wS = reinterpret_cast<const float4*>(&w1s[k * EHID])[c];
            float4 wT = reinterpret_cast<const float4*>(&w1s[(9 + k) * EHID])[c];
            aS.x += x[k] * wS.x; aS.y += x[k] * wS.y; aS.z += x[k] * wS.z; aS.w += x[k] * wS.w;
            aT.x += x[k] * wT.x; aT.y += x[k] * wT.y; aT.z += x[k] * wT.z; aT.w += x[k] * wT.w;
        }
        union { uint2 u; __half h[4]; } sv, tv;
        sv.h[0] = __float2half(aS.x); sv.h[1] = __float2half(aS.y);
        sv.h[2] = __float2half(aS.z); sv.h[3] = __float2half(aS.w);
        tv.h[0] = __float2half(aT.x); tv.h[1] = __float2half(aT.y);
        tv.h[2] = __float2half(aT.z); tv.h[3] = __float2half(aT.w);
        reinterpret_cast<uint2*>(preS + (size_t)i2 * EHID)[c] = sv.u;
        reinterpret_cast<uint2*>(preT + (size_t)i2 * EHID)[c] = tv.u;
        if (c == 1) {
            float sd0 = fmaxf(wstd[0], 1e-6f), sd1 = fmaxf(wstd[1], 1e-6f);
            float speed = fmaxf(x[7] * sd0 + wmean[0], 0.f);
            float wdir  = (x[8] * sd1 + wmean[1]) * 0.017453292519943295f;
            float2 wv; wv.x = 3.0f * speed; wv.y = wdir;
            wind2[i2] = wv;
        }
    }
}

extern "C" void kernel_launch(void* const* d_in, const int* in_sizes, int n_in,
                              void* d_out, int out_size, void* d_ws, size_t ws_size,
                              hipStream_t stream)
{
    const float* pm    = (const float*)d_in[0];
    const float* feat  = (const float*)d_in[1];
    const float* ea    = (const float*)d_in[2];
    const float* wmean = (const float*)d_in[3];
    const float* wstd  = (const float*)d_in[4];
    const float* ew1   = (const float*)d_in[5];
    const float* eb1   = (const float*)d_in[6];
    const float* ew2   = (const float*)d_in[7];
    const float* eb2   = (const float*)d_in[8];
    const float* nw    = (const float*)d_in[9];
    const float* nb    = (const float*)d_in[10];
    const float* wi    = (const float*)d_in[11];
    const float* wh    = (const float*)d_in[12];
    const float* bi    = (const float*)d_in[13];
    const float* bh    = (const float*)d_in[14];
    const float* fw    = (const float*)d_in[15];
    const float* fb    = (const float*)d_in[16];
    const int*   eidx  = (const int*)d_in[17];
    float* out = (float*)d_out;

    char* w = (char*)d_ws;
    double* partd = (double*)w;                    w += 256 * 4 * sizeof(double);
    float*  stats = (float*)w;                     w += 16 * sizeof(float);
    WPack*  wpack = (WPack*)w;                     w += EOUTC * sizeof(WPack);
    float4* epre4 = (float4*)w;                    w += (size_t)EE * sizeof(float4);
    float4* epreT = (float4*)w;                    w += (size_t)EE * sizeof(float4);
    float*  xncur = (float*)w;                     w += (size_t)BN * sizeof(float);
    __half2* hnA  = (__half2*)w;                   w += (size_t)32 * BN * sizeof(__half2);
    __half2* hnB  = (__half2*)w;                   w += (size_t)32 * BN * sizeof(__half2);
    __half* xcagg = (__half*)w;                    w += (size_t)BN * 16 * sizeof(__half);
    __half* preS  = (__half*)w;                    w += (size_t)BN * EHID * sizeof(__half);
    __half* preT  = (__half*)w;                    w += (size_t)BN * EHID * sizeof(__half);
    float2* wind2 = (float2*)w;                    w += (size_t)BN * sizeof(float2);
    __half* h3t   = (__half*)w;                    w += (size_t)BB * EE * 16 * sizeof(__half);
    __half* h3s   = (__half*)w;                    w += (size_t)BB * EE * 16 * sizeof(__half);
    __half* wi_h  = (__half*)w;                    w += (size_t)192 * GINC * sizeof(__half);
    __half* wh_h  = (__half*)w;                    w += (size_t)192 * HIDC * sizeof(__half);
    int4*   eT    = (int4*)w;                      w += (size_t)EE * sizeof(int4);
    int*    deg_t = (int*)w;                       w += NN * sizeof(int);
    int*    deg_s = (int*)w;                       w += NN * sizeof(int);
    int*    off_t = (int*)w;                       w += (NN + 1) * sizeof(int);
    int*    off_s = (int*)w;                       w += (NN + 1) * sizeof(int);
    int*    cnt_t = (int*)w;                       w += NN * sizeof(int);
    int*    cnt_s = (int*)w;                       w += NN * sizeof(int);

    stats1_kernel<<<256, 256, 0, stream>>>(ea, partd);
    stats2_kernel<<<1, 256, 0, stream>>>(partd, stats);
    hipMemsetAsync(deg_t, 0, 2 * NN * sizeof(int), stream);
    edgepre_kernel<<<(EE + 255) / 256, 256, 0, stream>>>(
        ea, stats, eidx, deg_t, deg_s, epre4);
    cvtw_kernel<<<(192 * HIDC + 255) / 256, 256, 0, stream>>>(
        wi, wh, ew2, eb2, nw, wi_h, wh_h, wpack);
    initxn_kernel<<<(BN + 255) / 256, 256, 0, stream>>>(pm, xncur);
    hipMemsetAsync(hnA, 0, (size_t)32 * BN * sizeof(__half2), stream);
    scan_kernel<<<1, 1024, 0, stream>>>(deg_t, deg_s, off_t, off_s, cnt_t, cnt_s);
    fillperm_kernel<<<(EE + 255) / 256, 256, 0, stream>>>(
        eidx, epre4, cnt_t, cnt_s, eT, epreT);
    pre_kernel<<<(BN * 8 + 255) / 256, 256, 0, stream>>>(
        xncur, feat, 0, ew1, wmean, wstd, preS, preT, wind2);

    for (int t = 0; t < PREDC; t++) {
        const __half2* hnold = (t & 1) ? hnB : hnA;
        __half2*       hnnew = (t & 1) ? hnA : hnB;
        edge_kernel<<<dim3(EE / 256, BB), 256, 0, stream>>>(
            eT, epreT, preS, preT, wind2, ew1, eb1, wpack, h3t, h3s);
        gather_kernel<<<(NN * 64 + 255) / 256, 256, 0, stream>>>(
            h3t, h3s, off_t, off_s, nb, xncur, xcagg);
        node_kernel<<<BN / 64, 1024, 0, stream>>>(
            xcagg, feat, t, wi_h, wh_h, bi, bh, fw, fb,
            hnold, hnnew, xncur, out,
            ew1, wmean, wstd, preS, preT, wind2);
    }
}

// Round 7
// 1116.954 us; speedup vs baseline: 1.1435x; 1.1435x over previous
//
#include <hip/hip_runtime.h>
#include <hip/hip_fp16.h>
#include <cstddef>

#define BB    4
#define NN    10000
#define EE    160000
#define BN    40000      // BB*NN
#define HISTC 8
#define PREDC 12
#define TSTEP 20         // HIST+PRED
#define FEX   8
#define HIDC  64
#define EHID  32
#define EOUTC 30
#define GOUTC 13
#define GINC  22         // GOUTC + 9

typedef float v2f __attribute__((ext_vector_type(2)));
typedef _Float16 v2h __attribute__((ext_vector_type(2)));

struct alignas(16) WPack {      // 128 B: one layer-2 output channel
    __half2 w[16];   // w2 row (32 halves)
    float   nw[14];  // folded n_w row (13 + pad)
    float   b2;
    float   pad;
};

__device__ __forceinline__ float fast_rcp(float x) { return __builtin_amdgcn_rcpf(x); }
__device__ __forceinline__ float sigm(float x) {
    return fast_rcp(1.0f + __expf(-x));
}
__device__ __forceinline__ v2f sigm2(v2f x) {
    v2f r; r.x = sigm(x.x); r.y = sigm(x.y); return r;
}
__device__ __forceinline__ float tanh_fast(float x) {
    x = fminf(fmaxf(x, -15.0f), 15.0f);
    float e = __expf(2.0f * x);
    return (e - 1.0f) * fast_rcp(e + 1.0f);
}

__device__ __forceinline__ float dot2(__half2 a, __half2 b, float c) {
#if __has_builtin(__builtin_amdgcn_fdot2)
    union { __half2 h; v2h v; } ua, ub;
    ua.h = a; ub.h = b;
    return __builtin_amdgcn_fdot2(ua.v, ub.v, c, false);
#else
    float2 fa = __half22float2(a), fb = __half22float2(b);
    return c + fa.x * fb.x + fa.y * fb.y;
#endif
}

// ---------------- edge_attr stats ---------------------------------------------
__global__ __launch_bounds__(256) void stats1_kernel(const float* __restrict__ ea,
                                                     double* __restrict__ part) {
    __shared__ double sm[256][4];
    int tid = threadIdx.x;
    double s0 = 0, s1 = 0, q0 = 0, q1 = 0;
    for (int e = blockIdx.x * 256 + tid; e < EE; e += 256 * 256) {
        float2 v = reinterpret_cast<const float2*>(ea)[e];
        double v0 = (double)v.x, v1 = (double)v.y;
        s0 += v0; q0 += v0 * v0;
        s1 += v1; q1 += v1 * v1;
    }
    sm[tid][0] = s0; sm[tid][1] = s1; sm[tid][2] = q0; sm[tid][3] = q1;
    __syncthreads();
    for (int off = 128; off > 0; off >>= 1) {
        if (tid < off)
            for (int k = 0; k < 4; k++) sm[tid][k] += sm[tid + off][k];
        __syncthreads();
    }
    if (tid == 0) {
        part[blockIdx.x * 4 + 0] = sm[0][0];
        part[blockIdx.x * 4 + 1] = sm[0][1];
        part[blockIdx.x * 4 + 2] = sm[0][2];
        part[blockIdx.x * 4 + 3] = sm[0][3];
    }
}

__global__ __launch_bounds__(256) void stats2_kernel(const double* __restrict__ part,
                                                     float* __restrict__ stats) {
    __shared__ double sm[256][4];
    int tid = threadIdx.x;
    sm[tid][0] = part[tid * 4 + 0];
    sm[tid][1] = part[tid * 4 + 1];
    sm[tid][2] = part[tid * 4 + 2];
    sm[tid][3] = part[tid * 4 + 3];
    __syncthreads();
    for (int off = 128; off > 0; off >>= 1) {
        if (tid < off)
            for (int k = 0; k < 4; k++) sm[tid][k] += sm[tid + off][k];
        __syncthreads();
    }
    if (tid == 0) {
        double m0 = sm[0][0] / EE, m1 = sm[0][1] / EE;
        double v0 = (sm[0][2] - sm[0][0] * sm[0][0] / EE) / (double)(EE - 1);
        double v1 = (sm[0][3] - sm[0][1] * sm[0][1] / EE) / (double)(EE - 1);
        float sd0 = fmaxf((float)sqrt(v0 > 0 ? v0 : 0.0), 1e-6f);
        float sd1 = fmaxf((float)sqrt(v1 > 0 ? v1 : 0.0), 1e-6f);
        stats[0] = (float)m0; stats[1] = (float)m1;
        stats[2] = 1.0f / sd0; stats[3] = 1.0f / sd1;
    }
}

// ---------------- per-edge precompute + degree histogram (fused) --------------
__global__ __launch_bounds__(256) void edgepre_kernel(
    const float* __restrict__ ea, const float* __restrict__ stats,
    const int* __restrict__ eidx,
    int* __restrict__ deg_t, int* __restrict__ deg_s,
    float4* __restrict__ epre4)
{
    int e = blockIdx.x * 256 + threadIdx.x;
    if (e >= EE) return;
    float2 v = reinterpret_cast<const float2*>(ea)[e];
    float4 r;
    r.x = (v.x - stats[0]) * stats[2];
    r.y = (v.y - stats[1]) * stats[3];
    r.z = 1.0f / fmaxf(v.x, 1e-3f);
    r.w = v.y;
    epre4[e] = r;
    atomicAdd(&deg_s[eidx[e]], 1);
    atomicAdd(&deg_t[eidx[EE + e]], 1);
}

// ---------------- weight conversion + WPack build (once per call) -------------
__global__ __launch_bounds__(256) void cvtw_kernel(
    const float* __restrict__ wi, const float* __restrict__ wh,
    const float* __restrict__ ew2, const float* __restrict__ eb2,
    const float* __restrict__ nw,
    __half* __restrict__ wi_h, __half* __restrict__ wh_h,
    WPack* __restrict__ wpack)
{
    int i = blockIdx.x * 256 + threadIdx.x;
    if (i < 192 * GINC) wi_h[i] = __float2half(wi[i]);
    if (i < 192 * HIDC) wh_h[i] = __float2half(wh[i]);
    if (i < EOUTC) {
        WPack wp;
        #pragma unroll
        for (int q = 0; q < 16; q++)
            wp.w[q] = __floats2half2_rn(ew2[(2 * q) * EOUTC + i],
                                        ew2[(2 * q + 1) * EOUTC + i]);
        #pragma unroll
        for (int j = 0; j < GOUTC; j++) wp.nw[j] = nw[i * GOUTC + j];
        wp.nw[13] = 0.f;
        wp.b2 = eb2[i];
        wp.pad = 0.f;
        wpack[i] = wp;
    }
}

// ---------------- xn init -----------------------------------------------------
__global__ void initxn_kernel(const float* __restrict__ pm, float* __restrict__ xn) {
    int i = blockIdx.x * 256 + threadIdx.x;
    if (i >= BN) return;
    int b = i / NN, n = i - b * NN;
    xn[i] = pm[(b * HISTC + (HISTC - 1)) * NN + n];
}

// ---------------- CSR scan ----------------------------------------------------
__global__ __launch_bounds__(1024) void scan_kernel(
    const int* __restrict__ deg_t, const int* __restrict__ deg_s,
    int* __restrict__ off_t, int* __restrict__ off_s,
    int* __restrict__ cnt_t, int* __restrict__ cnt_s)
{
    __shared__ int pt[1024], ps[1024];
    int tid = threadIdx.x;
    int base = tid * 10;
    int st = 0, ss = 0;
    for (int k = 0; k < 10; k++) {
        int i = base + k;
        if (i < NN) { st += deg_t[i]; ss += deg_s[i]; }
    }
    pt[tid] = st; ps[tid] = ss;
    __syncthreads();
    for (int off = 1; off < 1024; off <<= 1) {
        int vt = (tid >= off) ? pt[tid - off] : 0;
        int vs = (tid >= off) ? ps[tid - off] : 0;
        __syncthreads();
        pt[tid] += vt; ps[tid] += vs;
        __syncthreads();
    }
    int ext = (tid == 0) ? 0 : pt[tid - 1];
    int exs = (tid == 0) ? 0 : ps[tid - 1];
    for (int k = 0; k < 10; k++) {
        int i = base + k;
        if (i < NN) {
            off_t[i] = ext; cnt_t[i] = ext;
            off_s[i] = exs; cnt_s[i] = exs;
            ext += deg_t[i]; exs += deg_s[i];
        }
    }
    if (tid == 0) { off_t[NN] = EE; off_s[NN] = EE; }
}

// fill+perm fused: directly scatter eT[slot]={src,tgt,pos_s}, epreT[slot]
__global__ void fillperm_kernel(const int* __restrict__ eidx,
                                const float4* __restrict__ epre4,
                                int* __restrict__ cnt_t, int* __restrict__ cnt_s,
                                int4* __restrict__ eT, float4* __restrict__ epreT)
{
    int e = blockIdx.x * 256 + threadIdx.x;
    if (e >= EE) return;
    int s = eidx[e];
    int g = eidx[EE + e];
    int pt = atomicAdd(&cnt_t[g], 1);
    int ps = atomicAdd(&cnt_s[s], 1);
    int4 r; r.x = s; r.y = g; r.z = ps; r.w = 0;
    eT[pt] = r;
    epreT[pt] = epre4[e];
}

// ---------------- per-step node precompute (t=0 only; tail of node does t>0) --
__global__ __launch_bounds__(256) void pre_kernel(
    const float* __restrict__ xncur, const float* __restrict__ feature, int t,
    const float* __restrict__ ew1,
    const float* __restrict__ wmean, const float* __restrict__ wstd,
    __half* __restrict__ preS, __half* __restrict__ preT,
    float2* __restrict__ wind2)
{
    __shared__ alignas(16) float w1s[18 * EHID];
    for (int i = threadIdx.x; i < 18 * EHID; i += 256) w1s[i] = ew1[i];
    __syncthreads();
    int idx = blockIdx.x * 256 + threadIdx.x;
    if (idx >= BN * 8) return;
    int i = idx >> 3;
    int c = idx & 7;
    int b = i / NN, n = i - b * NN;
    float x[9];
    x[0] = xncur[i];
    {
        const float4* fp = reinterpret_cast<const float4*>(
            feature + (((size_t)b * TSTEP + HISTC + t) * NN + n) * FEX);
        float4 u = fp[0], v = fp[1];
        x[1] = u.x; x[2] = u.y; x[3] = u.z; x[4] = u.w;
        x[5] = v.x; x[6] = v.y; x[7] = v.z; x[8] = v.w;
    }
    float4 aS = {0.f, 0.f, 0.f, 0.f}, aT = {0.f, 0.f, 0.f, 0.f};
    #pragma unroll
    for (int k = 0; k < 9; k++) {
        float4 wS = reinterpret_cast<const float4*>(&w1s[k * EHID])[c];
        float4 wT = reinterpret_cast<const float4*>(&w1s[(9 + k) * EHID])[c];
        aS.x += x[k] * wS.x; aS.y += x[k] * wS.y; aS.z += x[k] * wS.z; aS.w += x[k] * wS.w;
        aT.x += x[k] * wT.x; aT.y += x[k] * wT.y; aT.z += x[k] * wT.z; aT.w += x[k] * wT.w;
    }
    union { uint2 u; __half h[4]; } sv, tv;
    sv.h[0] = __float2half(aS.x); sv.h[1] = __float2half(aS.y);
    sv.h[2] = __float2half(aS.z); sv.h[3] = __float2half(aS.w);
    tv.h[0] = __float2half(aT.x); tv.h[1] = __float2half(aT.y);
    tv.h[2] = __float2half(aT.z); tv.h[3] = __float2half(aT.w);
    reinterpret_cast<uint2*>(preS + (size_t)i * EHID)[c] = sv.u;
    reinterpret_cast<uint2*>(preT + (size_t)i * EHID)[c] = tv.u;
    if (c == 1) {
        float sd0 = fmaxf(wstd[0], 1e-6f), sd1 = fmaxf(wstd[1], 1e-6f);
        float speed = fmaxf(x[7] * sd0 + wmean[0], 0.f);
        float wdir  = (x[8] * sd1 + wmean[1]) * 0.017453292519943295f;
        float2 wv; wv.x = 3.0f * speed; wv.y = wdir;
        wind2[i] = wv;
    }
}

// ---------------- edge MLP, tgt-slot order, 1 batch/thread, grid (625,4) ------
// Round-0 body: scalar (wave-uniform) weight loads, no LDS staging.
__global__ __launch_bounds__(256) void edge_kernel(
    const int4* __restrict__ eT, const float4* __restrict__ epreT,
    const __half* __restrict__ preS, const __half* __restrict__ preT,
    const float2* __restrict__ wind2,
    const float* __restrict__ ew1, const float* __restrict__ eb1,
    const WPack* __restrict__ wpack,
    __half* __restrict__ h3t, __half* __restrict__ h3s)
{
    int i = blockIdx.x * 256 + threadIdx.x;   // slot (EE == 625*256, no tail)
    int b = blockIdx.y;
    int4 et = eT[i];
    int s = et.x, g = et.y, ps = et.z;
    float4 ep = epreT[i];          // {ean0, ean1, 1/dist, direc}

    size_t iS = (size_t)b * NN + s, iT = (size_t)b * NN + g;
    float2 wv2 = wind2[iS];
    float ew = fmaxf(wv2.x * __cosf(fabsf(ep.w - wv2.y)) * ep.z, 0.f);

    union alignas(16) { uint4 u[4]; __half2 h2[16]; } RS, RT;
    {
        const uint4* p;
        p = reinterpret_cast<const uint4*>(preS + iS * EHID);
        RS.u[0] = p[0]; RS.u[1] = p[1]; RS.u[2] = p[2]; RS.u[3] = p[3];
        p = reinterpret_cast<const uint4*>(preT + iT * EHID);
        RT.u[0] = p[0]; RT.u[1] = p[1]; RT.u[2] = p[2]; RT.u[3] = p[3];
    }

    const v2f* W18 = reinterpret_cast<const v2f*>(ew1 + 18 * EHID);
    const v2f* W19 = reinterpret_cast<const v2f*>(ew1 + 19 * EHID);
    const v2f* W20 = reinterpret_cast<const v2f*>(ew1 + 20 * EHID);
    const v2f* B1  = reinterpret_cast<const v2f*>(eb1);
    float ean0 = ep.x, ean1 = ep.y;
    __half2 h1h[16];
    #pragma unroll
    for (int q = 0; q < 16; q++) {
        v2f u = W18[q] * ean0 + W19[q] * ean1 + B1[q] + W20[q] * ew;
        float2 rs = __half22float2(RS.h2[q]);
        float2 rt = __half22float2(RT.h2[q]);
        u.x += rs.x + rt.x;
        u.y += rs.y + rt.y;
        v2f sg = sigm2(u);
        h1h[q] = __floats2half2_rn(sg.x, sg.y);
    }

    v2f h3p[7];
    #pragma unroll
    for (int j = 0; j < 7; j++) { h3p[j].x = 0.f; h3p[j].y = 0.f; }
    for (int o = 0; o < EOUTC; o++) {
        const WPack* W = wpack + o;
        float acc0 = W->b2, acc1 = 0.f;
        #pragma unroll
        for (int q = 0; q < 16; q += 2) {
            acc0 = dot2(h1h[q],     W->w[q],     acc0);
            acc1 = dot2(h1h[q + 1], W->w[q + 1], acc1);
        }
        float h2v = sigm(acc0 + acc1);
        const v2f* nr = reinterpret_cast<const v2f*>(W->nw);
        #pragma unroll
        for (int j = 0; j < 7; j++) h3p[j] += nr[j] * h2v;
    }

    union alignas(16) { uint4 u[2]; __half2 h2[8]; } r;
    #pragma unroll
    for (int j = 0; j < 7; j++) r.h2[j] = __floats2half2_rn(h3p[j].x, h3p[j].y);
    r.h2[7] = __floats2half2_rn(0.f, 0.f);
    {
        __half* oT = h3t + ((size_t)b * EE + i) * 16;     // coalesced
        reinterpret_cast<uint4*>(oT)[0] = r.u[0];
        reinterpret_cast<uint4*>(oT)[1] = r.u[1];
        __half* oS = h3s + ((size_t)b * EE + ps) * 16;    // scattered
        reinterpret_cast<uint4*>(oS)[0] = r.u[0];
        reinterpret_cast<uint4*>(oS)[1] = r.u[1];
    }
}

// ---------------- gather + gnn-out sigmoid -> fp16 xcagg (round-0) ------------
__global__ __launch_bounds__(256) void gather_kernel(
    const __half* __restrict__ h3t, const __half* __restrict__ h3s,
    const int* __restrict__ off_t, const int* __restrict__ off_s,
    const float* __restrict__ nb, const float* __restrict__ xncur,
    __half* __restrict__ xcagg)
{
    int n = (blockIdx.x * 256 + threadIdx.x) >> 6;
    if (n >= NN) return;
    n = __builtin_amdgcn_readfirstlane(n);
    int lane = threadIdx.x & 63;
    int b = lane >> 4, ch = lane & 15;
    const __half* ht = h3t + (size_t)b * EE * 16 + ch;
    const __half* hs = h3s + (size_t)b * EE * 16 + ch;
    float a0 = 0.f, a1 = 0.f, a2 = 0.f, a3 = 0.f;
    {
        int i0 = off_t[n], i1 = off_t[n + 1];
        int i = i0;
        for (; i + 4 <= i1; i += 4) {
            a0 += __half2float(ht[(size_t)(i + 0) * 16]);
            a1 += __half2float(ht[(size_t)(i + 1) * 16]);
            a2 += __half2float(ht[(size_t)(i + 2) * 16]);
            a3 += __half2float(ht[(size_t)(i + 3) * 16]);
        }
        for (; i < i1; i++) a0 += __half2float(ht[(size_t)i * 16]);
    }
    {
        int i0 = off_s[n], i1 = off_s[n + 1];
        int i = i0;
        for (; i + 4 <= i1; i += 4) {
            a0 -= __half2float(hs[(size_t)(i + 0) * 16]);
            a1 -= __half2float(hs[(size_t)(i + 1) * 16]);
            a2 -= __half2float(hs[(size_t)(i + 2) * 16]);
            a3 -= __half2float(hs[(size_t)(i + 3) * 16]);
        }
        for (; i < i1; i++) a0 -= __half2float(hs[(size_t)i * 16]);
    }
    float acc = (a0 + a1) + (a2 + a3);
    float val;
    if (ch < GOUTC) {
        val = sigm(acc + nb[ch]);
    } else if (ch == GOUTC) {
        val = xncur[(size_t)b * NN + n];
    } else {
        val = 0.f;
    }
    xcagg[((size_t)b * NN + n) * 16 + ch] = __float2half(val);
}

// ---------------- node: GRU merged 64-dims/block + fused pre(t+1) tail --------
// 625 blocks x 1024 thr = 10000 waves; j wave-uniform (readfirstlane) ->
// scalar weight loads. hh[] is ONLY indexed with compile-time constants
// (rule #20); the h_old value is re-read from LDS (runtime index into LDS ok).
__global__ __launch_bounds__(1024, 4) void node_kernel(
    const __half* __restrict__ xcagg, const float* __restrict__ feature, int t,
    const __half* __restrict__ wi_h, const __half* __restrict__ wh_h,
    const float* __restrict__ bi, const float* __restrict__ bh,
    const float* __restrict__ fw, const float* __restrict__ fb,
    const __half2* __restrict__ hnold, __half2* __restrict__ hnnew,
    float* __restrict__ xncur, float* __restrict__ out,
    const float* __restrict__ ew1,
    const float* __restrict__ wmean, const float* __restrict__ wstd,
    __half* __restrict__ preS, __half* __restrict__ preT,
    float2* __restrict__ wind2)
{
    __shared__ __half2 shh[32][65];       // 8320 B, +1 pad -> conflict-free
    __shared__ float xpart[16][64];       // 4096 B
    __shared__ alignas(16) float w1s[18 * EHID];   // 2304 B (for pre tail)
    __shared__ float xnewS[64];
    int tid  = threadIdx.x;
    int lane = tid & 63;
    int wav  = tid >> 6;                  // 16 waves
    int g0   = blockIdx.x * 64;           // 625 blocks, no tail

    // stage hnold for the block's 64 nodes + w1 table for the pre tail
    for (int k = tid; k < 32 * 64; k += 1024) {
        int p = k >> 6, l = k & 63;
        shh[p][l] = hnold[(size_t)p * BN + g0 + l];
    }
    if (tid < 18 * EHID) w1s[tid] = ew1[tid];
    __syncthreads();

    int node = g0 + lane;
    int b = node / NN;
    int n = node - b * NN;

    __half2 xch[11];
    {
        union alignas(16) { uint4 u[2]; __half2 h2[8]; } X;
        const uint4* xp16 = reinterpret_cast<const uint4*>(xcagg + (size_t)node * 16);
        X.u[0] = xp16[0]; X.u[1] = xp16[1];
        #pragma unroll
        for (int p = 0; p < 7; p++) xch[p] = X.h2[p];   // ch 0..13 (incl. xn)
    }
    {
        const float4* fp = reinterpret_cast<const float4*>(
            feature + (((size_t)b * TSTEP + HISTC + t) * NN + n) * FEX);
        float4 u = fp[0], v = fp[1];
        xch[7]  = __floats2half2_rn(u.x, u.y);
        xch[8]  = __floats2half2_rn(u.z, u.w);
        xch[9]  = __floats2half2_rn(v.x, v.y);
        xch[10] = __floats2half2_rn(v.z, v.w);
    }

    __half2 hh[32];
    #pragma unroll
    for (int p = 0; p < 32; p++) hh[p] = shh[p][lane];   // compile-time p only

    float hnew4[4];
    float xsum = 0.f;
    #pragma unroll
    for (int d = 0; d < 4; d++) {
        int j = __builtin_amdgcn_readfirstlane(wav * 4 + d);
        float ir = bi[j], iz = bi[64 + j], in_ = bi[128 + j];
        const __half2* wr0 = reinterpret_cast<const __half2*>(wi_h + (size_t)j * GINC);
        const __half2* wr1 = reinterpret_cast<const __half2*>(wi_h + (size_t)(64 + j) * GINC);
        const __half2* wr2 = reinterpret_cast<const __half2*>(wi_h + (size_t)(128 + j) * GINC);
        #pragma unroll
        for (int p = 0; p < 11; p++) {
            ir  = dot2(xch[p], wr0[p], ir);
            iz  = dot2(xch[p], wr1[p], iz);
            in_ = dot2(xch[p], wr2[p], in_);
        }
        float hr0 = bh[j], hz0 = bh[64 + j], hn0 = bh[128 + j];
        float hr1 = 0.f, hz1 = 0.f, hn1 = 0.f;
        const __half2* vr0 = reinterpret_cast<const __half2*>(wh_h + (size_t)j * HIDC);
        const __half2* vr1 = reinterpret_cast<const __half2*>(wh_h + (size_t)(64 + j) * HIDC);
        const __half2* vr2 = reinterpret_cast<const __half2*>(wh_h + (size_t)(128 + j) * HIDC);
        #pragma unroll
        for (int p = 0; p < 32; p += 2) {
            hr0 = dot2(hh[p],     vr0[p],     hr0);
            hz0 = dot2(hh[p],     vr1[p],     hz0);
            hn0 = dot2(hh[p],     vr2[p],     hn0);
            hr1 = dot2(hh[p + 1], vr0[p + 1], hr1);
            hz1 = dot2(hh[p + 1], vr1[p + 1], hz1);
            hn1 = dot2(hh[p + 1], vr2[p + 1], hn1);
        }
        float r  = sigm(ir + hr0 + hr1);
        float z  = sigm(iz + hz0 + hz1);
        float nl = tanh_fast(in_ + r * (hn0 + hn1));
        // h_old: runtime index goes to LDS (ds_read), NOT into hh[] registers
        union { __half2 h; __half v[2]; } hold2;
        hold2.h = shh[j >> 1][lane];
        float hold = __half2float(hold2.v[d & 1]);
        float hnew = (1.f - z) * nl + z * hold;
        hnew4[d] = hnew;
        xsum += hnew * fw[j];
    }
    hnnew[(size_t)(wav * 2) * BN + node]     = __floats2half2_rn(hnew4[0], hnew4[1]);
    hnnew[(size_t)(wav * 2 + 1) * BN + node] = __floats2half2_rn(hnew4[2], hnew4[3]);
    xpart[wav][lane] = xsum;
    __syncthreads();
    if (tid < 64) {
        float tot = 0.f;
        #pragma unroll
        for (int w2 = 0; w2 < 16; w2++) tot += xpart[w2][tid];
        int node2 = g0 + tid;
        float xnew = tot + fb[0];
        xncur[node2] = xnew;
        out[(size_t)node2 * PREDC + t] = xnew;
        xnewS[tid] = xnew;
    }
    __syncthreads();

    // ---- fused pre for step t+1 (threads 0..511; r0 pre math verbatim) ----
    if (t + 1 < PREDC && tid < 512) {
        int c  = tid & 7;
        int ln = tid >> 3;                 // 0..63
        int i2 = g0 + ln;
        int b2 = i2 / NN, n2 = i2 - b2 * NN;
        float x[9];
        x[0] = xnewS[ln];
        {
            const float4* fp = reinterpret_cast<const float4*>(
                feature + (((size_t)b2 * TSTEP + HISTC + (t + 1)) * NN + n2) * FEX);
            float4 u = fp[0], v = fp[1];
            x[1] = u.x; x[2] = u.y; x[3] = u.z; x[4] = u.w;
            x[5] = v.x; x[6] = v.y; x[7] = v.z; x[8] = v.w;
        }
        float4 aS = {0.f, 0.f, 0.f, 0.f}, aT = {0.f, 0.f, 0.f, 0.f};
        #pragma unroll
        for (int k = 0; k < 9; k++) {
            float4 wS = reinterpret_cast<const float4*>(&w1s[k * EHID])[c];
            float4 wT = reinterpret_cast<const float4*>(&w1s[(9 + k) * EHID])[c];
            aS.x += x[k] * wS.x; aS.y += x[k] * wS.y; aS.z += x[k] * wS.z; aS.w += x[k] * wS.w;
            aT.x += x[k] * wT.x; aT.y += x[k] * wT.y; aT.z += x[k] * wT.z; aT.w += x[k] * wT.w;
        }
        union { uint2 u; __half h[4]; } sv, tv;
        sv.h[0] = __float2half(aS.x); sv.h[1] = __float2half(aS.y);
        sv.h[2] = __float2half(aS.z); sv.h[3] = __float2half(aS.w);
        tv.h[0] = __float2half(aT.x); tv.h[1] = __float2half(aT.y);
        tv.h[2] = __float2half(aT.z); tv.h[3] = __float2half(aT.w);
        reinterpret_cast<uint2*>(preS + (size_t)i2 * EHID)[c] = sv.u;
        reinterpret_cast<uint2*>(preT + (size_t)i2 * EHID)[c] = tv.u;
        if (c == 1) {
            float sd0 = fmaxf(wstd[0], 1e-6f), sd1 = fmaxf(wstd[1], 1e-6f);
            float speed = fmaxf(x[7] * sd0 + wmean[0], 0.f);
            float wdir  = (x[8] * sd1 + wmean[1]) * 0.017453292519943295f;
            float2 wv; wv.x = 3.0f * speed; wv.y = wdir;
            wind2[i2] = wv;
        }
    }
}

extern "C" void kernel_launch(void* const* d_in, const int* in_sizes, int n_in,
                              void* d_out, int out_size, void* d_ws, size_t ws_size,
                              hipStream_t stream)
{
    const float* pm    = (const float*)d_in[0];
    const float* feat  = (const float*)d_in[1];
    const float* ea    = (const float*)d_in[2];
    const float* wmean = (const float*)d_in[3];
    const float* wstd  = (const float*)d_in[4];
    const float* ew1   = (const float*)d_in[5];
    const float* eb1   = (const float*)d_in[6];
    const float* ew2   = (const float*)d_in[7];
    const float* eb2   = (const float*)d_in[8];
    const float* nw    = (const float*)d_in[9];
    const float* nb    = (const float*)d_in[10];
    const float* wi    = (const float*)d_in[11];
    const float* wh    = (const float*)d_in[12];
    const float* bi    = (const float*)d_in[13];
    const float* bh    = (const float*)d_in[14];
    const float* fw    = (const float*)d_in[15];
    const float* fb    = (const float*)d_in[16];
    const int*   eidx  = (const int*)d_in[17];
    float* out = (float*)d_out;

    char* w = (char*)d_ws;
    double* partd = (double*)w;                    w += 256 * 4 * sizeof(double);
    float*  stats = (float*)w;                     w += 16 * sizeof(float);
    WPack*  wpack = (WPack*)w;                     w += EOUTC * sizeof(WPack);
    float4* epre4 = (float4*)w;                    w += (size_t)EE * sizeof(float4);
    float4* epreT = (float4*)w;                    w += (size_t)EE * sizeof(float4);
    float*  xncur = (float*)w;                     w += (size_t)BN * sizeof(float);
    __half2* hnA  = (__half2*)w;                   w += (size_t)32 * BN * sizeof(__half2);
    __half2* hnB  = (__half2*)w;                   w += (size_t)32 * BN * sizeof(__half2);
    __half* xcagg = (__half*)w;                    w += (size_t)BN * 16 * sizeof(__half);
    __half* preS  = (__half*)w;                    w += (size_t)BN * EHID * sizeof(__half);
    __half* preT  = (__half*)w;                    w += (size_t)BN * EHID * sizeof(__half);
    float2* wind2 = (float2*)w;                    w += (size_t)BN * sizeof(float2);
    __half* h3t   = (__half*)w;                    w += (size_t)BB * EE * 16 * sizeof(__half);
    __half* h3s   = (__half*)w;                    w += (size_t)BB * EE * 16 * sizeof(__half);
    __half* wi_h  = (__half*)w;                    w += (size_t)192 * GINC * sizeof(__half);
    __half* wh_h  = (__half*)w;                    w += (size_t)192 * HIDC * sizeof(__half);
    int4*   eT    = (int4*)w;                      w += (size_t)EE * sizeof(int4);
    int*    deg_t = (int*)w;                       w += NN * sizeof(int);
    int*    deg_s = (int*)w;                       w += NN * sizeof(int);
    int*    off_t = (int*)w;                       w += (NN + 1) * sizeof(int);
    int*    off_s = (int*)w;                       w += (NN + 1) * sizeof(int);
    int*    cnt_t = (int*)w;                       w += NN * sizeof(int);
    int*    cnt_s = (int*)w;                       w += NN * sizeof(int);

    stats1_kernel<<<256, 256, 0, stream>>>(ea, partd);
    stats2_kernel<<<1, 256, 0, stream>>>(partd, stats);
    hipMemsetAsync(deg_t, 0, 2 * NN * sizeof(int), stream);
    edgepre_kernel<<<(EE + 255) / 256, 256, 0, stream>>>(
        ea, stats, eidx, deg_t, deg_s, epre4);
    cvtw_kernel<<<(192 * HIDC + 255) / 256, 256, 0, stream>>>(
        wi, wh, ew2, eb2, nw, wi_h, wh_h, wpack);
    initxn_kernel<<<(BN + 255) / 256, 256, 0, stream>>>(pm, xncur);
    hipMemsetAsync(hnA, 0, (size_t)32 * BN * sizeof(__half2), stream);
    scan_kernel<<<1, 1024, 0, stream>>>(deg_t, deg_s, off_t, off_s, cnt_t, cnt_s);
    fillperm_kernel<<<(EE + 255) / 256, 256, 0, stream>>>(
        eidx, epre4, cnt_t, cnt_s, eT, epreT);
    pre_kernel<<<(BN * 8 + 255) / 256, 256, 0, stream>>>(
        xncur, feat, 0, ew1, wmean, wstd, preS, preT, wind2);

    for (int t = 0; t < PREDC; t++) {
        const __half2* hnold = (t & 1) ? hnB : hnA;
        __half2*       hnnew = (t & 1) ? hnA : hnB;
        edge_kernel<<<dim3(EE / 256, BB), 256, 0, stream>>>(
            eT, epreT, preS, preT, wind2, ew1, eb1, wpack, h3t, h3s);
        gather_kernel<<<(NN * 64 + 255) / 256, 256, 0, stream>>>(
            h3t, h3s, off_t, off_s, nb, xncur, xcagg);
        node_kernel<<<BN / 64, 1024, 0, stream>>>(
            xcagg, feat, t, wi_h, wh_h, bi, bh, fw, fb,
            hnold, hnnew, xncur, out,
            ew1, wmean, wstd, preS, preT, wind2);
    }
}

// Round 8
// 1044.935 us; speedup vs baseline: 1.2223x; 1.0689x over previous
//
#include <hip/hip_runtime.h>
#include <hip/hip_fp16.h>
#include <cstddef>

#define BB    4
#define NN    10000
#define EE    160000
#define BN    40000      // BB*NN
#define HISTC 8
#define PREDC 12
#define TSTEP 20         // HIST+PRED
#define FEX   8
#define HIDC  64
#define EHID  32
#define EOUTC 30
#define GOUTC 13
#define GINC  22         // GOUTC + 9

typedef float v2f __attribute__((ext_vector_type(2)));
typedef _Float16 v2h __attribute__((ext_vector_type(2)));

struct alignas(16) WPack {      // 128 B: one layer-2 output channel
    __half2 w[16];   // w2 row (32 halves)
    float   nw[14];  // folded n_w row (13 + pad)
    float   b2;
    float   pad;
};

__device__ __forceinline__ float fast_rcp(float x) { return __builtin_amdgcn_rcpf(x); }
__device__ __forceinline__ float sigm(float x) {
    return fast_rcp(1.0f + __expf(-x));
}
__device__ __forceinline__ v2f sigm2(v2f x) {
    v2f r; r.x = sigm(x.x); r.y = sigm(x.y); return r;
}
__device__ __forceinline__ float tanh_fast(float x) {
    x = fminf(fmaxf(x, -15.0f), 15.0f);
    float e = __expf(2.0f * x);
    return (e - 1.0f) * fast_rcp(e + 1.0f);
}

__device__ __forceinline__ float dot2(__half2 a, __half2 b, float c) {
#if __has_builtin(__builtin_amdgcn_fdot2)
    union { __half2 h; v2h v; } ua, ub;
    ua.h = a; ub.h = b;
    return __builtin_amdgcn_fdot2(ua.v, ub.v, c, false);
#else
    float2 fa = __half22float2(a), fb = __half22float2(b);
    return c + fa.x * fb.x + fa.y * fb.y;
#endif
}

// ---------------- edge_attr stats ---------------------------------------------
__global__ __launch_bounds__(256) void stats1_kernel(const float* __restrict__ ea,
                                                     double* __restrict__ part) {
    __shared__ double sm[256][4];
    int tid = threadIdx.x;
    double s0 = 0, s1 = 0, q0 = 0, q1 = 0;
    for (int e = blockIdx.x * 256 + tid; e < EE; e += 256 * 256) {
        float2 v = reinterpret_cast<const float2*>(ea)[e];
        double v0 = (double)v.x, v1 = (double)v.y;
        s0 += v0; q0 += v0 * v0;
        s1 += v1; q1 += v1 * v1;
    }
    sm[tid][0] = s0; sm[tid][1] = s1; sm[tid][2] = q0; sm[tid][3] = q1;
    __syncthreads();
    for (int off = 128; off > 0; off >>= 1) {
        if (tid < off)
            for (int k = 0; k < 4; k++) sm[tid][k] += sm[tid + off][k];
        __syncthreads();
    }
    if (tid == 0) {
        part[blockIdx.x * 4 + 0] = sm[0][0];
        part[blockIdx.x * 4 + 1] = sm[0][1];
        part[blockIdx.x * 4 + 2] = sm[0][2];
        part[blockIdx.x * 4 + 3] = sm[0][3];
    }
}

__global__ __launch_bounds__(256) void stats2_kernel(const double* __restrict__ part,
                                                     float* __restrict__ stats) {
    __shared__ double sm[256][4];
    int tid = threadIdx.x;
    sm[tid][0] = part[tid * 4 + 0];
    sm[tid][1] = part[tid * 4 + 1];
    sm[tid][2] = part[tid * 4 + 2];
    sm[tid][3] = part[tid * 4 + 3];
    __syncthreads();
    for (int off = 128; off > 0; off >>= 1) {
        if (tid < off)
            for (int k = 0; k < 4; k++) sm[tid][k] += sm[tid + off][k];
        __syncthreads();
    }
    if (tid == 0) {
        double m0 = sm[0][0] / EE, m1 = sm[0][1] / EE;
        double v0 = (sm[0][2] - sm[0][0] * sm[0][0] / EE) / (double)(EE - 1);
        double v1 = (sm[0][3] - sm[0][1] * sm[0][1] / EE) / (double)(EE - 1);
        float sd0 = fmaxf((float)sqrt(v0 > 0 ? v0 : 0.0), 1e-6f);
        float sd1 = fmaxf((float)sqrt(v1 > 0 ? v1 : 0.0), 1e-6f);
        stats[0] = (float)m0; stats[1] = (float)m1;
        stats[2] = 1.0f / sd0; stats[3] = 1.0f / sd1;
    }
}

// ---------------- per-edge precompute + degree histogram (fused) --------------
__global__ __launch_bounds__(256) void edgepre_kernel(
    const float* __restrict__ ea, const float* __restrict__ stats,
    const int* __restrict__ eidx,
    int* __restrict__ deg_t, int* __restrict__ deg_s,
    float4* __restrict__ epre4)
{
    int e = blockIdx.x * 256 + threadIdx.x;
    if (e >= EE) return;
    float2 v = reinterpret_cast<const float2*>(ea)[e];
    float4 r;
    r.x = (v.x - stats[0]) * stats[2];
    r.y = (v.y - stats[1]) * stats[3];
    r.z = 1.0f / fmaxf(v.x, 1e-3f);
    r.w = v.y;
    epre4[e] = r;
    atomicAdd(&deg_s[eidx[e]], 1);
    atomicAdd(&deg_t[eidx[EE + e]], 1);
}

// ---------------- weight conversion + WPack build (once per call) -------------
__global__ __launch_bounds__(256) void cvtw_kernel(
    const float* __restrict__ wi, const float* __restrict__ wh,
    const float* __restrict__ ew2, const float* __restrict__ eb2,
    const float* __restrict__ nw,
    __half* __restrict__ wi_h, __half* __restrict__ wh_h,
    WPack* __restrict__ wpack)
{
    int i = blockIdx.x * 256 + threadIdx.x;
    if (i < 192 * GINC) wi_h[i] = __float2half(wi[i]);
    if (i < 192 * HIDC) wh_h[i] = __float2half(wh[i]);
    if (i < EOUTC) {
        WPack wp;
        #pragma unroll
        for (int q = 0; q < 16; q++)
            wp.w[q] = __floats2half2_rn(ew2[(2 * q) * EOUTC + i],
                                        ew2[(2 * q + 1) * EOUTC + i]);
        #pragma unroll
        for (int j = 0; j < GOUTC; j++) wp.nw[j] = nw[i * GOUTC + j];
        wp.nw[13] = 0.f;
        wp.b2 = eb2[i];
        wp.pad = 0.f;
        wpack[i] = wp;
    }
}

// ---------------- xn init -----------------------------------------------------
__global__ void initxn_kernel(const float* __restrict__ pm, float* __restrict__ xn) {
    int i = blockIdx.x * 256 + threadIdx.x;
    if (i >= BN) return;
    int b = i / NN, n = i - b * NN;
    xn[i] = pm[(b * HISTC + (HISTC - 1)) * NN + n];
}

// ---------------- CSR scan ----------------------------------------------------
__global__ __launch_bounds__(1024) void scan_kernel(
    const int* __restrict__ deg_t, const int* __restrict__ deg_s,
    int* __restrict__ off_t, int* __restrict__ off_s,
    int* __restrict__ cnt_t, int* __restrict__ cnt_s)
{
    __shared__ int pt[1024], ps[1024];
    int tid = threadIdx.x;
    int base = tid * 10;
    int st = 0, ss = 0;
    for (int k = 0; k < 10; k++) {
        int i = base + k;
        if (i < NN) { st += deg_t[i]; ss += deg_s[i]; }
    }
    pt[tid] = st; ps[tid] = ss;
    __syncthreads();
    for (int off = 1; off < 1024; off <<= 1) {
        int vt = (tid >= off) ? pt[tid - off] : 0;
        int vs = (tid >= off) ? ps[tid - off] : 0;
        __syncthreads();
        pt[tid] += vt; ps[tid] += vs;
        __syncthreads();
    }
    int ext = (tid == 0) ? 0 : pt[tid - 1];
    int exs = (tid == 0) ? 0 : ps[tid - 1];
    for (int k = 0; k < 10; k++) {
        int i = base + k;
        if (i < NN) {
            off_t[i] = ext; cnt_t[i] = ext;
            off_s[i] = exs; cnt_s[i] = exs;
            ext += deg_t[i]; exs += deg_s[i];
        }
    }
    if (tid == 0) { off_t[NN] = EE; off_s[NN] = EE; }
}

// fill+perm fused: directly scatter eT[slot]={src,tgt,pos_s}, epreT[slot]
__global__ void fillperm_kernel(const int* __restrict__ eidx,
                                const float4* __restrict__ epre4,
                                int* __restrict__ cnt_t, int* __restrict__ cnt_s,
                                int4* __restrict__ eT, float4* __restrict__ epreT)
{
    int e = blockIdx.x * 256 + threadIdx.x;
    if (e >= EE) return;
    int s = eidx[e];
    int g = eidx[EE + e];
    int pt = atomicAdd(&cnt_t[g], 1);
    int ps = atomicAdd(&cnt_s[s], 1);
    int4 r; r.x = s; r.y = g; r.z = ps; r.w = 0;
    eT[pt] = r;
    epreT[pt] = epre4[e];
}

// ---------------- per-step node precompute (fp16 tables) + xn/out finalize ----
__global__ __launch_bounds__(256) void pre_kernel(
    float* __restrict__ xncur, const float* __restrict__ feature, int t,
    const float* __restrict__ xp,      // [4][BN] fc partials from node_kernel
    const float* __restrict__ fb,
    const float* __restrict__ ew1,
    const float* __restrict__ wmean, const float* __restrict__ wstd,
    __half* __restrict__ preS, __half* __restrict__ preT,
    float2* __restrict__ wind2, float* __restrict__ out)
{
    __shared__ alignas(16) float w1s[18 * EHID];
    for (int i = threadIdx.x; i < 18 * EHID; i += 256) w1s[i] = ew1[i];
    __syncthreads();
    int idx = blockIdx.x * 256 + threadIdx.x;
    if (idx >= BN * 8) return;
    int i = idx >> 3;
    int c = idx & 7;
    int b = i / NN, n = i - b * NN;
    float x0;
    if (t == 0) {
        x0 = xncur[i];
    } else {
        x0 = (xp[i] + xp[BN + i]) + (xp[2 * BN + i] + xp[3 * BN + i]) + fb[0];
        if (c == 0) {
            xncur[i] = x0;
            out[(size_t)i * PREDC + (t - 1)] = x0;
        }
    }
    float x[9];
    x[0] = x0;
    {
        const float4* fp = reinterpret_cast<const float4*>(
            feature + (((size_t)b * TSTEP + HISTC + t) * NN + n) * FEX);
        float4 u = fp[0], v = fp[1];
        x[1] = u.x; x[2] = u.y; x[3] = u.z; x[4] = u.w;
        x[5] = v.x; x[6] = v.y; x[7] = v.z; x[8] = v.w;
    }
    float4 aS = {0.f, 0.f, 0.f, 0.f}, aT = {0.f, 0.f, 0.f, 0.f};
    #pragma unroll
    for (int k = 0; k < 9; k++) {
        float4 wS = reinterpret_cast<const float4*>(&w1s[k * EHID])[c];
        float4 wT = reinterpret_cast<const float4*>(&w1s[(9 + k) * EHID])[c];
        aS.x += x[k] * wS.x; aS.y += x[k] * wS.y; aS.z += x[k] * wS.z; aS.w += x[k] * wS.w;
        aT.x += x[k] * wT.x; aT.y += x[k] * wT.y; aT.z += x[k] * wT.z; aT.w += x[k] * wT.w;
    }
    union { uint2 u; __half h[4]; } sv, tv;
    sv.h[0] = __float2half(aS.x); sv.h[1] = __float2half(aS.y);
    sv.h[2] = __float2half(aS.z); sv.h[3] = __float2half(aS.w);
    tv.h[0] = __float2half(aT.x); tv.h[1] = __float2half(aT.y);
    tv.h[2] = __float2half(aT.z); tv.h[3] = __float2half(aT.w);
    reinterpret_cast<uint2*>(preS + (size_t)i * EHID)[c] = sv.u;
    reinterpret_cast<uint2*>(preT + (size_t)i * EHID)[c] = tv.u;
    if (c == 1) {
        float sd0 = fmaxf(wstd[0], 1e-6f), sd1 = fmaxf(wstd[1], 1e-6f);
        float speed = fmaxf(x[7] * sd0 + wmean[0], 0.f);
        float wdir  = (x[8] * sd1 + wmean[1]) * 0.017453292519943295f;
        float2 wv; wv.x = 3.0f * speed; wv.y = wdir;
        wind2[i] = wv;
    }
}

__global__ __launch_bounds__(256) void finalout_kernel(
    const float* __restrict__ xp, const float* __restrict__ fb,
    float* __restrict__ out)
{
    int i = blockIdx.x * 256 + threadIdx.x;
    if (i >= BN) return;
    out[(size_t)i * PREDC + (PREDC - 1)] =
        (xp[i] + xp[BN + i]) + (xp[2 * BN + i] + xp[3 * BN + i]) + fb[0];
}

// ---------------- edge MLP, tgt-slot order, 1 batch/thread, grid (625,4) ------
__global__ __launch_bounds__(256) void edge_kernel(
    const int4* __restrict__ eT, const float4* __restrict__ epreT,
    const __half* __restrict__ preS, const __half* __restrict__ preT,
    const float2* __restrict__ wind2,
    const float* __restrict__ ew1, const float* __restrict__ eb1,
    const WPack* __restrict__ wpack,
    __half* __restrict__ h3t, __half* __restrict__ h3s)
{
    int i = blockIdx.x * 256 + threadIdx.x;   // slot (EE == 625*256, no tail)
    int b = blockIdx.y;
    int4 et = eT[i];
    int s = et.x, g = et.y, ps = et.z;
    float4 ep = epreT[i];          // {ean0, ean1, 1/dist, direc}

    size_t iS = (size_t)b * NN + s, iT = (size_t)b * NN + g;
    float2 wv2 = wind2[iS];
    float ew = fmaxf(wv2.x * __cosf(fabsf(ep.w - wv2.y)) * ep.z, 0.f);

    union alignas(16) { uint4 u[4]; __half2 h2[16]; } RS, RT;
    {
        const uint4* p;
        p = reinterpret_cast<const uint4*>(preS + iS * EHID);
        RS.u[0] = p[0]; RS.u[1] = p[1]; RS.u[2] = p[2]; RS.u[3] = p[3];
        p = reinterpret_cast<const uint4*>(preT + iT * EHID);
        RT.u[0] = p[0]; RT.u[1] = p[1]; RT.u[2] = p[2]; RT.u[3] = p[3];
    }

    const v2f* W18 = reinterpret_cast<const v2f*>(ew1 + 18 * EHID);
    const v2f* W19 = reinterpret_cast<const v2f*>(ew1 + 19 * EHID);
    const v2f* W20 = reinterpret_cast<const v2f*>(ew1 + 20 * EHID);
    const v2f* B1  = reinterpret_cast<const v2f*>(eb1);
    float ean0 = ep.x, ean1 = ep.y;
    __half2 h1h[16];
    #pragma unroll
    for (int q = 0; q < 16; q++) {
        v2f u = W18[q] * ean0 + W19[q] * ean1 + B1[q] + W20[q] * ew;
        float2 rs = __half22float2(RS.h2[q]);
        float2 rt = __half22float2(RT.h2[q]);
        u.x += rs.x + rt.x;
        u.y += rs.y + rt.y;
        v2f sg = sigm2(u);
        h1h[q] = __floats2half2_rn(sg.x, sg.y);
    }

    v2f h3p[7];
    #pragma unroll
    for (int j = 0; j < 7; j++) { h3p[j].x = 0.f; h3p[j].y = 0.f; }
    for (int o = 0; o < EOUTC; o++) {
        const WPack* W = wpack + o;
        float acc0 = W->b2, acc1 = 0.f;
        #pragma unroll
        for (int q = 0; q < 16; q += 2) {
            acc0 = dot2(h1h[q],     W->w[q],     acc0);
            acc1 = dot2(h1h[q + 1], W->w[q + 1], acc1);
        }
        float h2v = sigm(acc0 + acc1);
        const v2f* nr = reinterpret_cast<const v2f*>(W->nw);
        #pragma unroll
        for (int j = 0; j < 7; j++) h3p[j] += nr[j] * h2v;
    }

    union alignas(16) { uint4 u[2]; __half2 h2[8]; } r;
    #pragma unroll
    for (int j = 0; j < 7; j++) r.h2[j] = __floats2half2_rn(h3p[j].x, h3p[j].y);
    r.h2[7] = __floats2half2_rn(0.f, 0.f);
    {
        __half* oT = h3t + ((size_t)b * EE + i) * 16;     // coalesced
        reinterpret_cast<uint4*>(oT)[0] = r.u[0];
        reinterpret_cast<uint4*>(oT)[1] = r.u[1];
        __half* oS = h3s + ((size_t)b * EE + ps) * 16;    // scattered
        reinterpret_cast<uint4*>(oS)[0] = r.u[0];
        reinterpret_cast<uint4*>(oS)[1] = r.u[1];
    }
}

// ---------------- gather: quad-tiled coalesced CSR sum -> fp16 xcagg ----------
// Wave = node. lane = (b, e4, chq): lane loads uint2 (4 channels, 8 B) for
// edge slot i0+e4, stepping i += 4 -> each 16-lane b-group covers 4 slots
// x 32 B = ONE contiguous 128 B segment per instruction (4x fewer loads,
// 4x better coalescing vs per-half layout). e4 partials folded by shfl_xor.
__global__ __launch_bounds__(256) void gather_kernel(
    const __half* __restrict__ h3t, const __half* __restrict__ h3s,
    const int* __restrict__ off_t, const int* __restrict__ off_s,
    const float* __restrict__ nb, const float* __restrict__ xncur,
    __half* __restrict__ xcagg)
{
    int n = (blockIdx.x * 256 + threadIdx.x) >> 6;
    if (n >= NN) return;
    n = __builtin_amdgcn_readfirstlane(n);
    int lane = threadIdx.x & 63;
    int b   = lane >> 4;          // batch
    int e4  = (lane >> 2) & 3;    // edge-slot offset within group of 4
    int chq = lane & 3;           // channel quad: channels [chq*4, chq*4+4)

    const __half* ht = h3t + (size_t)b * ((size_t)EE * 16) + chq * 4;
    const __half* hs = h3s + (size_t)b * ((size_t)EE * 16) + chq * 4;

    float a0 = 0.f, a1 = 0.f, a2 = 0.f, a3 = 0.f;
    {
        int i0 = off_t[n], i1 = off_t[n + 1];
        for (int i = i0 + e4; i < i1; i += 4) {
            uint2 v = *reinterpret_cast<const uint2*>(ht + (size_t)i * 16);
            float2 f01 = __half22float2(*reinterpret_cast<__half2*>(&v.x));
            float2 f23 = __half22float2(*reinterpret_cast<__half2*>(&v.y));
            a0 += f01.x; a1 += f01.y; a2 += f23.x; a3 += f23.y;
        }
    }
    {
        int i0 = off_s[n], i1 = off_s[n + 1];
        for (int i = i0 + e4; i < i1; i += 4) {
            uint2 v = *reinterpret_cast<const uint2*>(hs + (size_t)i * 16);
            float2 f01 = __half22float2(*reinterpret_cast<__half2*>(&v.x));
            float2 f23 = __half22float2(*reinterpret_cast<__half2*>(&v.y));
            a0 -= f01.x; a1 -= f01.y; a2 -= f23.x; a3 -= f23.y;
        }
    }
    // fold e4 partials (lane bits 2,3)
    a0 += __shfl_xor(a0, 4); a1 += __shfl_xor(a1, 4);
    a2 += __shfl_xor(a2, 4); a3 += __shfl_xor(a3, 4);
    a0 += __shfl_xor(a0, 8); a1 += __shfl_xor(a1, 8);
    a2 += __shfl_xor(a2, 8); a3 += __shfl_xor(a3, 8);

    if (e4 == 0) {
        int c0 = chq * 4;
        // nb has exactly GOUTC=13 floats: clamp indices to avoid OOB loads.
        float nb0 = nb[c0 < GOUTC ? c0 : GOUTC - 1];
        float nb1 = nb[c0 + 1 < GOUTC ? c0 + 1 : GOUTC - 1];
        float nb2 = nb[c0 + 2 < GOUTC ? c0 + 2 : GOUTC - 1];
        float nb3 = nb[c0 + 3 < GOUTC ? c0 + 3 : GOUTC - 1];
        float v0 = (c0 + 0 < GOUTC) ? sigm(a0 + nb0) : 0.f;
        float v1 = (c0 + 1 < GOUTC) ? sigm(a1 + nb1)
                 : ((c0 + 1 == GOUTC) ? xncur[(size_t)b * NN + n] : 0.f);
        float v2 = (c0 + 2 < GOUTC) ? sigm(a2 + nb2) : 0.f;
        float v3 = (c0 + 3 < GOUTC) ? sigm(a3 + nb3) : 0.f;
        union { uint2 u; __half h[4]; } o;
        o.h[0] = __float2half(v0); o.h[1] = __float2half(v1);
        o.h[2] = __float2half(v2); o.h[3] = __float2half(v3);
        *reinterpret_cast<uint2*>(xcagg + ((size_t)b * NN + n) * 16 + c0) = o.u;
    }
}

// ---------------- node: GRU (fp16 dot2) + fc partial (round-0 verbatim) -------
// grid (BN/64, 4); wave w of block (.,jb) handles dims [jb*16 + w*4, +4).
__global__ __launch_bounds__(256) void node_kernel(
    const __half* __restrict__ xcagg, const float* __restrict__ feature, int t,
    const __half* __restrict__ wi_h, const __half* __restrict__ wh_h,
    const float* __restrict__ bi, const float* __restrict__ bh,
    const float* __restrict__ fw,
    const __half2* __restrict__ hnold, __half2* __restrict__ hnnew,
    float* __restrict__ xp)
{
    __shared__ float xpart[4][64];
    int lane = threadIdx.x & 63;
    int wav  = threadIdx.x >> 6;
    int jb   = blockIdx.y;
    int node = blockIdx.x * 64 + lane;
    int b = node / NN;
    int n = node - b * NN;

    __half2 xch[11];
    {
        union alignas(16) { uint4 u[2]; __half2 h2[8]; } X;
        const uint4* xp16 = reinterpret_cast<const uint4*>(xcagg + (size_t)node * 16);
        X.u[0] = xp16[0]; X.u[1] = xp16[1];
        #pragma unroll
        for (int p = 0; p < 7; p++) xch[p] = X.h2[p];   // ch 0..13 (incl. xn)
    }
    {
        const float4* fp = reinterpret_cast<const float4*>(
            feature + (((size_t)b * TSTEP + HISTC + t) * NN + n) * FEX);
        float4 u = fp[0], v = fp[1];
        xch[7]  = __floats2half2_rn(u.x, u.y);
        xch[8]  = __floats2half2_rn(u.z, u.w);
        xch[9]  = __floats2half2_rn(v.x, v.y);
        xch[10] = __floats2half2_rn(v.z, v.w);
    }

    __half2 hh[32];
    #pragma unroll
    for (int p = 0; p < 32; p++) hh[p] = hnold[(size_t)p * BN + node];

    float xsum = 0.f;
    #pragma unroll
    for (int jj2 = 0; jj2 < 2; jj2++) {
        int j0 = __builtin_amdgcn_readfirstlane(jb * 16 + wav * 4 + jj2 * 2);
        union { __half2 h; __half v[2]; } holdw;
        holdw.h = hnold[(size_t)(j0 >> 1) * BN + node];
        float hnew2[2];
        #pragma unroll
        for (int d = 0; d < 2; d++) {
            int j = j0 + d;
            float ir = bi[j], iz = bi[64 + j], in_ = bi[128 + j];
            const __half2* wr0 = reinterpret_cast<const __half2*>(wi_h + (size_t)j * GINC);
            const __half2* wr1 = reinterpret_cast<const __half2*>(wi_h + (size_t)(64 + j) * GINC);
            const __half2* wr2 = reinterpret_cast<const __half2*>(wi_h + (size_t)(128 + j) * GINC);
            #pragma unroll
            for (int p = 0; p < 11; p++) {
                ir  = dot2(xch[p], wr0[p], ir);
                iz  = dot2(xch[p], wr1[p], iz);
                in_ = dot2(xch[p], wr2[p], in_);
            }
            float hr0 = bh[j], hz0 = bh[64 + j], hn0 = bh[128 + j];
            float hr1 = 0.f, hz1 = 0.f, hn1 = 0.f;
            const __half2* vr0 = reinterpret_cast<const __half2*>(wh_h + (size_t)j * HIDC);
            const __half2* vr1 = reinterpret_cast<const __half2*>(wh_h + (size_t)(64 + j) * HIDC);
            const __half2* vr2 = reinterpret_cast<const __half2*>(wh_h + (size_t)(128 + j) * HIDC);
            #pragma unroll
            for (int p = 0; p < 32; p += 2) {
                hr0 = dot2(hh[p],     vr0[p],     hr0);
                hz0 = dot2(hh[p],     vr1[p],     hz0);
                hn0 = dot2(hh[p],     vr2[p],     hn0);
                hr1 = dot2(hh[p + 1], vr0[p + 1], hr1);
                hz1 = dot2(hh[p + 1], vr1[p + 1], hz1);
                hn1 = dot2(hh[p + 1], vr2[p + 1], hn1);
            }
            float r  = sigm(ir + hr0 + hr1);
            float z  = sigm(iz + hz0 + hz1);
            float nn = tanh_fast(in_ + r * (hn0 + hn1));
            float hold = __half2float(holdw.v[d]);
            float hnew = (1.f - z) * nn + z * hold;
            hnew2[d] = hnew;
            xsum += hnew * fw[j];
        }
        hnnew[(size_t)(j0 >> 1) * BN + node] = __floats2half2_rn(hnew2[0], hnew2[1]);
    }
    xpart[wav][lane] = xsum;
    __syncthreads();
    if (wav == 0) {
        float tot = xpart[0][lane] + xpart[1][lane] + xpart[2][lane] + xpart[3][lane];
        xp[(size_t)jb * BN + node] = tot;
    }
}

extern "C" void kernel_launch(void* const* d_in, const int* in_sizes, int n_in,
                              void* d_out, int out_size, void* d_ws, size_t ws_size,
                              hipStream_t stream)
{
    const float* pm    = (const float*)d_in[0];
    const float* feat  = (const float*)d_in[1];
    const float* ea    = (const float*)d_in[2];
    const float* wmean = (const float*)d_in[3];
    const float* wstd  = (const float*)d_in[4];
    const float* ew1   = (const float*)d_in[5];
    const float* eb1   = (const float*)d_in[6];
    const float* ew2   = (const float*)d_in[7];
    const float* eb2   = (const float*)d_in[8];
    const float* nw    = (const float*)d_in[9];
    const float* nb    = (const float*)d_in[10];
    const float* wi    = (const float*)d_in[11];
    const float* wh    = (const float*)d_in[12];
    const float* bi    = (const float*)d_in[13];
    const float* bh    = (const float*)d_in[14];
    const float* fw    = (const float*)d_in[15];
    const float* fb    = (const float*)d_in[16];
    const int*   eidx  = (const int*)d_in[17];
    float* out = (float*)d_out;

    char* w = (char*)d_ws;
    double* partd = (double*)w;                    w += 256 * 4 * sizeof(double);
    float*  stats = (float*)w;                     w += 16 * sizeof(float);
    WPack*  wpack = (WPack*)w;                     w += EOUTC * sizeof(WPack);
    float4* epre4 = (float4*)w;                    w += (size_t)EE * sizeof(float4);
    float4* epreT = (float4*)w;                    w += (size_t)EE * sizeof(float4);
    float*  xncur = (float*)w;                     w += (size_t)BN * sizeof(float);
    float*  xp    = (float*)w;                     w += (size_t)4 * BN * sizeof(float);
    __half2* hnA  = (__half2*)w;                   w += (size_t)32 * BN * sizeof(__half2);
    __half2* hnB  = (__half2*)w;                   w += (size_t)32 * BN * sizeof(__half2);
    __half* xcagg = (__half*)w;                    w += (size_t)BN * 16 * sizeof(__half);
    __half* preS  = (__half*)w;                    w += (size_t)BN * EHID * sizeof(__half);
    __half* preT  = (__half*)w;                    w += (size_t)BN * EHID * sizeof(__half);
    float2* wind2 = (float2*)w;                    w += (size_t)BN * sizeof(float2);
    __half* h3t   = (__half*)w;                    w += (size_t)BB * EE * 16 * sizeof(__half);
    __half* h3s   = (__half*)w;                    w += (size_t)BB * EE * 16 * sizeof(__half);
    __half* wi_h  = (__half*)w;                    w += (size_t)192 * GINC * sizeof(__half);
    __half* wh_h  = (__half*)w;                    w += (size_t)192 * HIDC * sizeof(__half);
    int*    deg_t = (int*)w;                       w += NN * sizeof(int);
    int*    deg_s = (int*)w;                       w += NN * sizeof(int);
    int*    off_t = (int*)w;                       w += (NN + 1) * sizeof(int);
    int*    off_s = (int*)w;                       w += (NN + 1) * sizeof(int);
    int*    cnt_t = (int*)w;                       w += NN * sizeof(int);
    int*    cnt_s = (int*)w;                       w += NN * sizeof(int);
    int4*   eT    = (int4*)w;                      w += (size_t)EE * sizeof(int4);

    stats1_kernel<<<256, 256, 0, stream>>>(ea, partd);
    stats2_kernel<<<1, 256, 0, stream>>>(partd, stats);
    hipMemsetAsync(deg_t, 0, 2 * NN * sizeof(int), stream);
    edgepre_kernel<<<(EE + 255) / 256, 256, 0, stream>>>(
        ea, stats, eidx, deg_t, deg_s, epre4);
    cvtw_kernel<<<(192 * HIDC + 255) / 256, 256, 0, stream>>>(
        wi, wh, ew2, eb2, nw, wi_h, wh_h, wpack);
    initxn_kernel<<<(BN + 255) / 256, 256, 0, stream>>>(pm, xncur);
    hipMemsetAsync(hnA, 0, (size_t)32 * BN * sizeof(__half2), stream);
    scan_kernel<<<1, 1024, 0, stream>>>(deg_t, deg_s, off_t, off_s, cnt_t, cnt_s);
    fillperm_kernel<<<(EE + 255) / 256, 256, 0, stream>>>(
        eidx, epre4, cnt_t, cnt_s, eT, epreT);

    for (int t = 0; t < PREDC; t++) {
        const __half2* hnold = (t & 1) ? hnB : hnA;
        __half2*       hnnew = (t & 1) ? hnA : hnB;
        pre_kernel<<<(BN * 8 + 255) / 256, 256, 0, stream>>>(
            xncur, feat, t, xp, fb, ew1, wmean, wstd, preS, preT, wind2, out);
        edge_kernel<<<dim3(EE / 256, BB), 256, 0, stream>>>(
            eT, epreT, preS, preT, wind2, ew1, eb1, wpack, h3t, h3s);
        gather_kernel<<<(NN * 64 + 255) / 256, 256, 0, stream>>>(
            h3t, h3s, off_t, off_s, nb, xncur, xcagg);
        node_kernel<<<dim3(BN / 64, 4), 256, 0, stream>>>(
            xcagg, feat, t, wi_h, wh_h, bi, bh, fw, hnold, hnnew, xp);
    }
    finalout_kernel<<<(BN + 255) / 256, 256, 0, stream>>>(xp, fb, out);
}

// Round 9
// 928.567 us; speedup vs baseline: 1.3755x; 1.1253x over previous
//
#include <hip/hip_runtime.h>
#include <hip/hip_fp16.h>
#include <cstddef>

#define BB    4
#define NN    10000
#define EE    160000
#define BN    40000      // BB*NN
#define HISTC 8
#define PREDC 12
#define TSTEP 20         // HIST+PRED
#define FEX   8
#define HIDC  64
#define EHID  32
#define EOUTC 30
#define GOUTC 13
#define GINC  22         // GOUTC + 9

typedef float v2f __attribute__((ext_vector_type(2)));
typedef _Float16 v2h __attribute__((ext_vector_type(2)));
typedef _Float16 v8h __attribute__((ext_vector_type(8)));
typedef float f32x4 __attribute__((ext_vector_type(4)));

struct alignas(16) WPack {      // 128 B: one layer-2 output channel (legacy)
    __half2 w[16];   // w2 row (32 halves)
    float   nw[14];  // folded n_w row (13 + pad)
    float   b2;
    float   pad;
};

__device__ __forceinline__ float fast_rcp(float x) { return __builtin_amdgcn_rcpf(x); }
__device__ __forceinline__ float sigm(float x) {
    return fast_rcp(1.0f + __expf(-x));
}
__device__ __forceinline__ v2f sigm2(v2f x) {
    v2f r; r.x = sigm(x.x); r.y = sigm(x.y); return r;
}
__device__ __forceinline__ float tanh_fast(float x) {
    x = fminf(fmaxf(x, -15.0f), 15.0f);
    float e = __expf(2.0f * x);
    return (e - 1.0f) * fast_rcp(e + 1.0f);
}

__device__ __forceinline__ float dot2(__half2 a, __half2 b, float c) {
#if __has_builtin(__builtin_amdgcn_fdot2)
    union { __half2 h; v2h v; } ua, ub;
    ua.h = a; ub.h = b;
    return __builtin_amdgcn_fdot2(ua.v, ub.v, c, false);
#else
    float2 fa = __half22float2(a), fb = __half22float2(b);
    return c + fa.x * fb.x + fa.y * fb.y;
#endif
}

// ---------------- edge_attr stats ---------------------------------------------
__global__ __launch_bounds__(256) void stats1_kernel(const float* __restrict__ ea,
                                                     double* __restrict__ part) {
    __shared__ double sm[256][4];
    int tid = threadIdx.x;
    double s0 = 0, s1 = 0, q0 = 0, q1 = 0;
    for (int e = blockIdx.x * 256 + tid; e < EE; e += 256 * 256) {
        float2 v = reinterpret_cast<const float2*>(ea)[e];
        double v0 = (double)v.x, v1 = (double)v.y;
        s0 += v0; q0 += v0 * v0;
        s1 += v1; q1 += v1 * v1;
    }
    sm[tid][0] = s0; sm[tid][1] = s1; sm[tid][2] = q0; sm[tid][3] = q1;
    __syncthreads();
    for (int off = 128; off > 0; off >>= 1) {
        if (tid < off)
            for (int k = 0; k < 4; k++) sm[tid][k] += sm[tid + off][k];
        __syncthreads();
    }
    if (tid == 0) {
        part[blockIdx.x * 4 + 0] = sm[0][0];
        part[blockIdx.x * 4 + 1] = sm[0][1];
        part[blockIdx.x * 4 + 2] = sm[0][2];
        part[blockIdx.x * 4 + 3] = sm[0][3];
    }
}

__global__ __launch_bounds__(256) void stats2_kernel(const double* __restrict__ part,
                                                     float* __restrict__ stats) {
    __shared__ double sm[256][4];
    int tid = threadIdx.x;
    sm[tid][0] = part[tid * 4 + 0];
    sm[tid][1] = part[tid * 4 + 1];
    sm[tid][2] = part[tid * 4 + 2];
    sm[tid][3] = part[tid * 4 + 3];
    __syncthreads();
    for (int off = 128; off > 0; off >>= 1) {
        if (tid < off)
            for (int k = 0; k < 4; k++) sm[tid][k] += sm[tid + off][k];
        __syncthreads();
    }
    if (tid == 0) {
        double m0 = sm[0][0] / EE, m1 = sm[0][1] / EE;
        double v0 = (sm[0][2] - sm[0][0] * sm[0][0] / EE) / (double)(EE - 1);
        double v1 = (sm[0][3] - sm[0][1] * sm[0][1] / EE) / (double)(EE - 1);
        float sd0 = fmaxf((float)sqrt(v0 > 0 ? v0 : 0.0), 1e-6f);
        float sd1 = fmaxf((float)sqrt(v1 > 0 ? v1 : 0.0), 1e-6f);
        stats[0] = (float)m0; stats[1] = (float)m1;
        stats[2] = 1.0f / sd0; stats[3] = 1.0f / sd1;
    }
}

// ---------------- per-edge precompute + degree histogram (fused) --------------
__global__ __launch_bounds__(256) void edgepre_kernel(
    const float* __restrict__ ea, const float* __restrict__ stats,
    const int* __restrict__ eidx,
    int* __restrict__ deg_t, int* __restrict__ deg_s,
    float4* __restrict__ epre4)
{
    int e = blockIdx.x * 256 + threadIdx.x;
    if (e >= EE) return;
    float2 v = reinterpret_cast<const float2*>(ea)[e];
    float4 r;
    r.x = (v.x - stats[0]) * stats[2];
    r.y = (v.y - stats[1]) * stats[3];
    r.z = 1.0f / fmaxf(v.x, 1e-3f);
    r.w = v.y;
    epre4[e] = r;
    atomicAdd(&deg_s[eidx[e]], 1);
    atomicAdd(&deg_t[eidx[EE + e]], 1);
}

// ---------------- weight conversion + MFMA B-operand build (once per call) ----
// w2b: [32 o][32 k] f16 col-major W2 (o>=30 zero). nwb: [16 j][32 o] f16 n_w^T
// (j>=13 or o>=30 zero -> h3 channels 13..15 exact zeros).
__global__ __launch_bounds__(256) void cvtw_kernel(
    const float* __restrict__ wi, const float* __restrict__ wh,
    const float* __restrict__ ew2, const float* __restrict__ eb2,
    const float* __restrict__ nw,
    __half* __restrict__ wi_h, __half* __restrict__ wh_h,
    __half* __restrict__ w2b, __half* __restrict__ nwb)
{
    int i = blockIdx.x * 256 + threadIdx.x;
    if (i < 192 * GINC) wi_h[i] = __float2half(wi[i]);
    if (i < 192 * HIDC) wh_h[i] = __float2half(wh[i]);
    if (i < 32 * 32) {
        int o = i >> 5, k = i & 31;
        w2b[i] = (o < EOUTC) ? __float2half(ew2[k * EOUTC + o]) : __half(0.0f);
    }
    if (i < 16 * 32) {
        int j = i >> 5, o = i & 31;
        nwb[i] = (j < GOUTC && o < EOUTC) ? __float2half(nw[o * GOUTC + j])
                                          : __half(0.0f);
    }
}

// ---------------- xn init -----------------------------------------------------
__global__ void initxn_kernel(const float* __restrict__ pm, float* __restrict__ xn) {
    int i = blockIdx.x * 256 + threadIdx.x;
    if (i >= BN) return;
    int b = i / NN, n = i - b * NN;
    xn[i] = pm[(b * HISTC + (HISTC - 1)) * NN + n];
}

// ---------------- CSR scan ----------------------------------------------------
__global__ __launch_bounds__(1024) void scan_kernel(
    const int* __restrict__ deg_t, const int* __restrict__ deg_s,
    int* __restrict__ off_t, int* __restrict__ off_s,
    int* __restrict__ cnt_t, int* __restrict__ cnt_s)
{
    __shared__ int pt[1024], ps[1024];
    int tid = threadIdx.x;
    int base = tid * 10;
    int st = 0, ss = 0;
    for (int k = 0; k < 10; k++) {
        int i = base + k;
        if (i < NN) { st += deg_t[i]; ss += deg_s[i]; }
    }
    pt[tid] = st; ps[tid] = ss;
    __syncthreads();
    for (int off = 1; off < 1024; off <<= 1) {
        int vt = (tid >= off) ? pt[tid - off] : 0;
        int vs = (tid >= off) ? ps[tid - off] : 0;
        __syncthreads();
        pt[tid] += vt; ps[tid] += vs;
        __syncthreads();
    }
    int ext = (tid == 0) ? 0 : pt[tid - 1];
    int exs = (tid == 0) ? 0 : ps[tid - 1];
    for (int k = 0; k < 10; k++) {
        int i = base + k;
        if (i < NN) {
            off_t[i] = ext; cnt_t[i] = ext;
            off_s[i] = exs; cnt_s[i] = exs;
            ext += deg_t[i]; exs += deg_s[i];
        }
    }
    if (tid == 0) { off_t[NN] = EE; off_s[NN] = EE; }
}

// fill+perm fused: directly scatter eT[slot]={src,tgt,pos_s}, epreT[slot]
__global__ void fillperm_kernel(const int* __restrict__ eidx,
                                const float4* __restrict__ epre4,
                                int* __restrict__ cnt_t, int* __restrict__ cnt_s,
                                int4* __restrict__ eT, float4* __restrict__ epreT)
{
    int e = blockIdx.x * 256 + threadIdx.x;
    if (e >= EE) return;
    int s = eidx[e];
    int g = eidx[EE + e];
    int pt = atomicAdd(&cnt_t[g], 1);
    int ps = atomicAdd(&cnt_s[s], 1);
    int4 r; r.x = s; r.y = g; r.z = ps; r.w = 0;
    eT[pt] = r;
    epreT[pt] = epre4[e];
}

// ---------------- per-step node precompute (fp16 tables) + xn/out finalize ----
__global__ __launch_bounds__(256) void pre_kernel(
    float* __restrict__ xncur, const float* __restrict__ feature, int t,
    const float* __restrict__ xp,      // [4][BN] fc partials from node_kernel
    const float* __restrict__ fb,
    const float* __restrict__ ew1,
    const float* __restrict__ wmean, const float* __restrict__ wstd,
    __half* __restrict__ preS, __half* __restrict__ preT,
    float2* __restrict__ wind2, float* __restrict__ out)
{
    __shared__ alignas(16) float w1s[18 * EHID];
    for (int i = threadIdx.x; i < 18 * EHID; i += 256) w1s[i] = ew1[i];
    __syncthreads();
    int idx = blockIdx.x * 256 + threadIdx.x;
    if (idx >= BN * 8) return;
    int i = idx >> 3;
    int c = idx & 7;
    int b = i / NN, n = i - b * NN;
    float x0;
    if (t == 0) {
        x0 = xncur[i];
    } else {
        x0 = (xp[i] + xp[BN + i]) + (xp[2 * BN + i] + xp[3 * BN + i]) + fb[0];
        if (c == 0) {
            xncur[i] = x0;
            out[(size_t)i * PREDC + (t - 1)] = x0;
        }
    }
    float x[9];
    x[0] = x0;
    {
        const float4* fp = reinterpret_cast<const float4*>(
            feature + (((size_t)b * TSTEP + HISTC + t) * NN + n) * FEX);
        float4 u = fp[0], v = fp[1];
        x[1] = u.x; x[2] = u.y; x[3] = u.z; x[4] = u.w;
        x[5] = v.x; x[6] = v.y; x[7] = v.z; x[8] = v.w;
    }
    float4 aS = {0.f, 0.f, 0.f, 0.f}, aT = {0.f, 0.f, 0.f, 0.f};
    #pragma unroll
    for (int k = 0; k < 9; k++) {
        float4 wS = reinterpret_cast<const float4*>(&w1s[k * EHID])[c];
        float4 wT = reinterpret_cast<const float4*>(&w1s[(9 + k) * EHID])[c];
        aS.x += x[k] * wS.x; aS.y += x[k] * wS.y; aS.z += x[k] * wS.z; aS.w += x[k] * wS.w;
        aT.x += x[k] * wT.x; aT.y += x[k] * wT.y; aT.z += x[k] * wT.z; aT.w += x[k] * wT.w;
    }
    union { uint2 u; __half h[4]; } sv, tv;
    sv.h[0] = __float2half(aS.x); sv.h[1] = __float2half(aS.y);
    sv.h[2] = __float2half(aS.z); sv.h[3] = __float2half(aS.w);
    tv.h[0] = __float2half(aT.x); tv.h[1] = __float2half(aT.y);
    tv.h[2] = __float2half(aT.z); tv.h[3] = __float2half(aT.w);
    reinterpret_cast<uint2*>(preS + (size_t)i * EHID)[c] = sv.u;
    reinterpret_cast<uint2*>(preT + (size_t)i * EHID)[c] = tv.u;
    if (c == 1) {
        float sd0 = fmaxf(wstd[0], 1e-6f), sd1 = fmaxf(wstd[1], 1e-6f);
        float speed = fmaxf(x[7] * sd0 + wmean[0], 0.f);
        float wdir  = (x[8] * sd1 + wmean[1]) * 0.017453292519943295f;
        float2 wv; wv.x = 3.0f * speed; wv.y = wdir;
        wind2[i] = wv;
    }
}

__global__ __launch_bounds__(256) void finalout_kernel(
    const float* __restrict__ xp, const float* __restrict__ fb,
    float* __restrict__ out)
{
    int i = blockIdx.x * 256 + threadIdx.x;
    if (i >= BN) return;
    out[(size_t)i * PREDC + (PREDC - 1)] =
        (xp[i] + xp[BN + i]) + (xp[2 * BN + i] + xp[3 * BN + i]) + fb[0];
}

// ---------------- edge MLP with MFMA layer-2 + n_w fold -----------------------
// Layer 1 per-thread (identical to r0). Then per wave (64 edges), all
// wave-LOCAL LDS (no barriers; each wave reads only its own writes):
//   h1 (f16) -> LDS row-major -> 4 M-tiles x 2 N-tiles mfma_f32_16x16x32_f16
//   (h2 = h1 @ W2) -> sigmoid on C-frags -> S(f16) -> 4 MFMAs (h3 = S @ nw^T,
//   j>=13 rows zeroed) -> LDS transpose -> r0's coalesced h3t/h3s stores.
// A-frag mapping assumed: lane l holds A[row=l%16][k=8*(l/16)+i] (std CDNA).
#define H1STR 40   // halves; 80 B rows, 16B-aligned, 2-way banks
#define S2STR 36   // halves; 72 B rows, 8B-aligned (b64 reads), conflict-free
__global__ __launch_bounds__(256) void edge_kernel(
    const int4* __restrict__ eT, const float4* __restrict__ epreT,
    const __half* __restrict__ preS, const __half* __restrict__ preT,
    const float2* __restrict__ wind2,
    const float* __restrict__ ew1, const float* __restrict__ eb1,
    const __half* __restrict__ w2b, const __half* __restrict__ nwb,
    const float* __restrict__ eb2,
    __half* __restrict__ h3t, __half* __restrict__ h3s)
{
    __shared__ alignas(16) __half h1s[256 * H1STR];   // 20480 B
    __shared__ alignas(16) __half s2s[4][16 * S2STR]; //  4608 B
    __shared__ alignas(16) __half h3x[256 * 16];      //  8192 B

    int tid  = threadIdx.x;
    int lane = tid & 63, wv = tid >> 6;
    int l15  = lane & 15, lk = lane >> 4;
    int i = blockIdx.x * 256 + tid;   // slot (EE == 625*256, no tail)
    int b = blockIdx.y;
    int4 et = eT[i];
    int s = et.x, g = et.y, ps = et.z;
    float4 ep = epreT[i];          // {ean0, ean1, 1/dist, direc}

    size_t iS = (size_t)b * NN + s, iT = (size_t)b * NN + g;
    float2 wvd = wind2[iS];
    float ew = fmaxf(wvd.x * __cosf(fabsf(ep.w - wvd.y)) * ep.z, 0.f);

    // MFMA B-fragments + biases (loaded once; L2-resident)
    v8h bw2a, bw2b, bnw;
    {
        union { uint4 u; v8h h; } t;
        t.u = *reinterpret_cast<const uint4*>(w2b + l15 * 32 + lk * 8);        bw2a = t.h;
        t.u = *reinterpret_cast<const uint4*>(w2b + (16 + l15) * 32 + lk * 8); bw2b = t.h;
        t.u = *reinterpret_cast<const uint4*>(nwb + l15 * 32 + lk * 8);        bnw  = t.h;
    }
    float b2v0 = eb2[l15];
    float b2v1 = eb2[(16 + l15) < EOUTC ? (16 + l15) : (EOUTC - 1)];

    union alignas(16) { uint4 u[4]; __half2 h2[16]; } RS, RT;
    {
        const uint4* p;
        p = reinterpret_cast<const uint4*>(preS + iS * EHID);
        RS.u[0] = p[0]; RS.u[1] = p[1]; RS.u[2] = p[2]; RS.u[3] = p[3];
        p = reinterpret_cast<const uint4*>(preT + iT * EHID);
        RT.u[0] = p[0]; RT.u[1] = p[1]; RT.u[2] = p[2]; RT.u[3] = p[3];
    }

    const v2f* W18 = reinterpret_cast<const v2f*>(ew1 + 18 * EHID);
    const v2f* W19 = reinterpret_cast<const v2f*>(ew1 + 19 * EHID);
    const v2f* W20 = reinterpret_cast<const v2f*>(ew1 + 20 * EHID);
    const v2f* B1  = reinterpret_cast<const v2f*>(eb1);
    float ean0 = ep.x, ean1 = ep.y;
    union alignas(16) { uint4 u[4]; __half2 h2[16]; } H1;
    #pragma unroll
    for (int q = 0; q < 16; q++) {
        v2f u = W18[q] * ean0 + W19[q] * ean1 + B1[q] + W20[q] * ew;
        float2 rs = __half22float2(RS.h2[q]);
        float2 rt = __half22float2(RT.h2[q]);
        u.x += rs.x + rt.x;
        u.y += rs.y + rt.y;
        v2f sg = sigm2(u);
        H1.h2[q] = __floats2half2_rn(sg.x, sg.y);
    }
    {   // stage h1 row (64 B) to LDS
        uint4* dst = reinterpret_cast<uint4*>(h1s + tid * H1STR);
        dst[0] = H1.u[0]; dst[1] = H1.u[1]; dst[2] = H1.u[2]; dst[3] = H1.u[3];
    }

    f32x4 zero = {0.f, 0.f, 0.f, 0.f};
    __half* s2w = s2s[wv];
    #pragma unroll
    for (int mt = 0; mt < 4; ++mt) {
        v8h af;
        {
            union { uint4 u; v8h h; } t;
            t.u = *reinterpret_cast<const uint4*>(
                h1s + (wv * 64 + mt * 16 + l15) * H1STR + lk * 8);
            af = t.h;
        }
        f32x4 a0 = __builtin_amdgcn_mfma_f32_16x16x32_f16(af, bw2a, zero, 0, 0, 0);
        f32x4 a1 = __builtin_amdgcn_mfma_f32_16x16x32_f16(af, bw2b, zero, 0, 0, 0);
        // C layout: col(o-within-tile)=lane&15, row(edge)=lk*4+q
        #pragma unroll
        for (int q = 0; q < 4; ++q) {
            int rl = lk * 4 + q;
            s2w[rl * S2STR + l15]      = __float2half(sigm(a0[q] + b2v0));
            s2w[rl * S2STR + 16 + l15] = __float2half(sigm(a1[q] + b2v1));
        }
        v8h a2;
        {
            union { uint2 u[2]; v8h h; } t;
            const __half* p2 = s2w + l15 * S2STR + lk * 8;
            t.u[0] = *reinterpret_cast<const uint2*>(p2);
            t.u[1] = *reinterpret_cast<const uint2*>(p2 + 4);
            a2 = t.h;
        }
        f32x4 h3a = __builtin_amdgcn_mfma_f32_16x16x32_f16(a2, bnw, zero, 0, 0, 0);
        #pragma unroll
        for (int q = 0; q < 4; ++q) {
            h3x[(wv * 64 + mt * 16 + lk * 4 + q) * 16 + l15] = __float2half(h3a[q]);
        }
    }

    // read own edge's 16 channels (incl. exact-zero 13..15), store like r0
    union alignas(16) { uint4 u[2]; } R;
    R.u[0] = *reinterpret_cast<const uint4*>(h3x + tid * 16);
    R.u[1] = *reinterpret_cast<const uint4*>(h3x + tid * 16 + 8);
    {
        __half* oT = h3t + ((size_t)b * EE + i) * 16;     // coalesced
        reinterpret_cast<uint4*>(oT)[0] = R.u[0];
        reinterpret_cast<uint4*>(oT)[1] = R.u[1];
        __half* oS = h3s + ((size_t)b * EE + ps) * 16;    // scattered
        reinterpret_cast<uint4*>(oS)[0] = R.u[0];
        reinterpret_cast<uint4*>(oS)[1] = R.u[1];
    }
}

// ---------------- gather: quad-tiled coalesced CSR sum -> fp16 xcagg ----------
__global__ __launch_bounds__(256) void gather_kernel(
    const __half* __restrict__ h3t, const __half* __restrict__ h3s,
    const int* __restrict__ off_t, const int* __restrict__ off_s,
    const float* __restrict__ nb, const float* __restrict__ xncur,
    __half* __restrict__ xcagg)
{
    int n = (blockIdx.x * 256 + threadIdx.x) >> 6;
    if (n >= NN) return;
    n = __builtin_amdgcn_readfirstlane(n);
    int lane = threadIdx.x & 63;
    int b   = lane >> 4;          // batch
    int e4  = (lane >> 2) & 3;    // edge-slot offset within group of 4
    int chq = lane & 3;           // channel quad: channels [chq*4, chq*4+4)

    const __half* ht = h3t + (size_t)b * ((size_t)EE * 16) + chq * 4;
    const __half* hs = h3s + (size_t)b * ((size_t)EE * 16) + chq * 4;

    float a0 = 0.f, a1 = 0.f, a2 = 0.f, a3 = 0.f;
    {
        int i0 = off_t[n], i1 = off_t[n + 1];
        for (int i = i0 + e4; i < i1; i += 4) {
            uint2 v = *reinterpret_cast<const uint2*>(ht + (size_t)i * 16);
            float2 f01 = __half22float2(*reinterpret_cast<__half2*>(&v.x));
            float2 f23 = __half22float2(*reinterpret_cast<__half2*>(&v.y));
            a0 += f01.x; a1 += f01.y; a2 += f23.x; a3 += f23.y;
        }
    }
    {
        int i0 = off_s[n], i1 = off_s[n + 1];
        for (int i = i0 + e4; i < i1; i += 4) {
            uint2 v = *reinterpret_cast<const uint2*>(hs + (size_t)i * 16);
            float2 f01 = __half22float2(*reinterpret_cast<__half2*>(&v.x));
            float2 f23 = __half22float2(*reinterpret_cast<__half2*>(&v.y));
            a0 -= f01.x; a1 -= f01.y; a2 -= f23.x; a3 -= f23.y;
        }
    }
    // fold e4 partials (lane bits 2,3)
    a0 += __shfl_xor(a0, 4); a1 += __shfl_xor(a1, 4);
    a2 += __shfl_xor(a2, 4); a3 += __shfl_xor(a3, 4);
    a0 += __shfl_xor(a0, 8); a1 += __shfl_xor(a1, 8);
    a2 += __shfl_xor(a2, 8); a3 += __shfl_xor(a3, 8);

    if (e4 == 0) {
        int c0 = chq * 4;
        float nb0 = nb[c0 < GOUTC ? c0 : GOUTC - 1];
        float nb1 = nb[c0 + 1 < GOUTC ? c0 + 1 : GOUTC - 1];
        float nb2 = nb[c0 + 2 < GOUTC ? c0 + 2 : GOUTC - 1];
        float nb3 = nb[c0 + 3 < GOUTC ? c0 + 3 : GOUTC - 1];
        float v0 = (c0 + 0 < GOUTC) ? sigm(a0 + nb0) : 0.f;
        float v1 = (c0 + 1 < GOUTC) ? sigm(a1 + nb1)
                 : ((c0 + 1 == GOUTC) ? xncur[(size_t)b * NN + n] : 0.f);
        float v2 = (c0 + 2 < GOUTC) ? sigm(a2 + nb2) : 0.f;
        float v3 = (c0 + 3 < GOUTC) ? sigm(a3 + nb3) : 0.f;
        union { uint2 u; __half h[4]; } o;
        o.h[0] = __float2half(v0); o.h[1] = __float2half(v1);
        o.h[2] = __float2half(v2); o.h[3] = __float2half(v3);
        *reinterpret_cast<uint2*>(xcagg + ((size_t)b * NN + n) * 16 + c0) = o.u;
    }
}

// ---------------- node: GRU (fp16 dot2) + fc partial (round-0 verbatim) -------
__global__ __launch_bounds__(256) void node_kernel(
    const __half* __restrict__ xcagg, const float* __restrict__ feature, int t,
    const __half* __restrict__ wi_h, const __half* __restrict__ wh_h,
    const float* __restrict__ bi, const float* __restrict__ bh,
    const float* __restrict__ fw,
    const __half2* __restrict__ hnold, __half2* __restrict__ hnnew,
    float* __restrict__ xp)
{
    __shared__ float xpart[4][64];
    int lane = threadIdx.x & 63;
    int wav  = threadIdx.x >> 6;
    int jb   = blockIdx.y;
    int node = blockIdx.x * 64 + lane;
    int b = node / NN;
    int n = node - b * NN;

    __half2 xch[11];
    {
        union alignas(16) { uint4 u[2]; __half2 h2[8]; } X;
        const uint4* xp16 = reinterpret_cast<const uint4*>(xcagg + (size_t)node * 16);
        X.u[0] = xp16[0]; X.u[1] = xp16[1];
        #pragma unroll
        for (int p = 0; p < 7; p++) xch[p] = X.h2[p];   // ch 0..13 (incl. xn)
    }
    {
        const float4* fp = reinterpret_cast<const float4*>(
            feature + (((size_t)b * TSTEP + HISTC + t) * NN + n) * FEX);
        float4 u = fp[0], v = fp[1];
        xch[7]  = __floats2half2_rn(u.x, u.y);
        xch[8]  = __floats2half2_rn(u.z, u.w);
        xch[9]  = __floats2half2_rn(v.x, v.y);
        xch[10] = __floats2half2_rn(v.z, v.w);
    }

    __half2 hh[32];
    #pragma unroll
    for (int p = 0; p < 32; p++) hh[p] = hnold[(size_t)p * BN + node];

    float xsum = 0.f;
    #pragma unroll
    for (int jj2 = 0; jj2 < 2; jj2++) {
        int j0 = __builtin_amdgcn_readfirstlane(jb * 16 + wav * 4 + jj2 * 2);
        union { __half2 h; __half v[2]; } holdw;
        holdw.h = hnold[(size_t)(j0 >> 1) * BN + node];
        float hnew2[2];
        #pragma unroll
        for (int d = 0; d < 2; d++) {
            int j = j0 + d;
            float ir = bi[j], iz = bi[64 + j], in_ = bi[128 + j];
            const __half2* wr0 = reinterpret_cast<const __half2*>(wi_h + (size_t)j * GINC);
            const __half2* wr1 = reinterpret_cast<const __half2*>(wi_h + (size_t)(64 + j) * GINC);
            const __half2* wr2 = reinterpret_cast<const __half2*>(wi_h + (size_t)(128 + j) * GINC);
            #pragma unroll
            for (int p = 0; p < 11; p++) {
                ir  = dot2(xch[p], wr0[p], ir);
                iz  = dot2(xch[p], wr1[p], iz);
                in_ = dot2(xch[p], wr2[p], in_);
            }
            float hr0 = bh[j], hz0 = bh[64 + j], hn0 = bh[128 + j];
            float hr1 = 0.f, hz1 = 0.f, hn1 = 0.f;
            const __half2* vr0 = reinterpret_cast<const __half2*>(wh_h + (size_t)j * HIDC);
            const __half2* vr1 = reinterpret_cast<const __half2*>(wh_h + (size_t)(64 + j) * HIDC);
            const __half2* vr2 = reinterpret_cast<const __half2*>(wh_h + (size_t)(128 + j) * HIDC);
            #pragma unroll
            for (int p = 0; p < 32; p += 2) {
                hr0 = dot2(hh[p],     vr0[p],     hr0);
                hz0 = dot2(hh[p],     vr1[p],     hz0);
                hn0 = dot2(hh[p],     vr2[p],     hn0);
                hr1 = dot2(hh[p + 1], vr0[p + 1], hr1);
                hz1 = dot2(hh[p + 1], vr1[p + 1], hz1);
                hn1 = dot2(hh[p + 1], vr2[p + 1], hn1);
            }
            float r  = sigm(ir + hr0 + hr1);
            float z  = sigm(iz + hz0 + hz1);
            float nn = tanh_fast(in_ + r * (hn0 + hn1));
            float hold = __half2float(holdw.v[d]);
            float hnew = (1.f - z) * nn + z * hold;
            hnew2[d] = hnew;
            xsum += hnew * fw[j];
        }
        hnnew[(size_t)(j0 >> 1) * BN + node] = __floats2half2_rn(hnew2[0], hnew2[1]);
    }
    xpart[wav][lane] = xsum;
    __syncthreads();
    if (wav == 0) {
        float tot = xpart[0][lane] + xpart[1][lane] + xpart[2][lane] + xpart[3][lane];
        xp[(size_t)jb * BN + node] = tot;
    }
}

extern "C" void kernel_launch(void* const* d_in, const int* in_sizes, int n_in,
                              void* d_out, int out_size, void* d_ws, size_t ws_size,
                              hipStream_t stream)
{
    const float* pm    = (const float*)d_in[0];
    const float* feat  = (const float*)d_in[1];
    const float* ea    = (const float*)d_in[2];
    const float* wmean = (const float*)d_in[3];
    const float* wstd  = (const float*)d_in[4];
    const float* ew1   = (const float*)d_in[5];
    const float* eb1   = (const float*)d_in[6];
    const float* ew2   = (const float*)d_in[7];
    const float* eb2   = (const float*)d_in[8];
    const float* nw    = (const float*)d_in[9];
    const float* nb    = (const float*)d_in[10];
    const float* wi    = (const float*)d_in[11];
    const float* wh    = (const float*)d_in[12];
    const float* bi    = (const float*)d_in[13];
    const float* bh    = (const float*)d_in[14];
    const float* fw    = (const float*)d_in[15];
    const float* fb    = (const float*)d_in[16];
    const int*   eidx  = (const int*)d_in[17];
    float* out = (float*)d_out;

    char* w = (char*)d_ws;
    double* partd = (double*)w;                    w += 256 * 4 * sizeof(double);
    float*  stats = (float*)w;                     w += 16 * sizeof(float);
    float4* epre4 = (float4*)w;                    w += (size_t)EE * sizeof(float4);
    float4* epreT = (float4*)w;                    w += (size_t)EE * sizeof(float4);
    float*  xncur = (float*)w;                     w += (size_t)BN * sizeof(float);
    float*  xp    = (float*)w;                     w += (size_t)4 * BN * sizeof(float);
    __half2* hnA  = (__half2*)w;                   w += (size_t)32 * BN * sizeof(__half2);
    __half2* hnB  = (__half2*)w;                   w += (size_t)32 * BN * sizeof(__half2);
    __half* xcagg = (__half*)w;                    w += (size_t)BN * 16 * sizeof(__half);
    __half* preS  = (__half*)w;                    w += (size_t)BN * EHID * sizeof(__half);
    __half* preT  = (__half*)w;                    w += (size_t)BN * EHID * sizeof(__half);
    float2* wind2 = (float2*)w;                    w += (size_t)BN * sizeof(float2);
    __half* h3t   = (__half*)w;                    w += (size_t)BB * EE * 16 * sizeof(__half);
    __half* h3s   = (__half*)w;                    w += (size_t)BB * EE * 16 * sizeof(__half);
    __half* wi_h  = (__half*)w;                    w += (size_t)192 * GINC * sizeof(__half);
    __half* wh_h  = (__half*)w;                    w += (size_t)192 * HIDC * sizeof(__half);
    __half* w2b   = (__half*)w;                    w += (size_t)32 * 32 * sizeof(__half);
    __half* nwb   = (__half*)w;                    w += (size_t)16 * 32 * sizeof(__half);
    int*    deg_t = (int*)w;                       w += NN * sizeof(int);
    int*    deg_s = (int*)w;                       w += NN * sizeof(int);
    int*    off_t = (int*)w;                       w += (NN + 1) * sizeof(int);
    int*    off_s = (int*)w;                       w += (NN + 1) * sizeof(int);
    int*    cnt_t = (int*)w;                       w += NN * sizeof(int);
    int*    cnt_s = (int*)w;                       w += NN * sizeof(int);
    int4*   eT    = (int4*)w;                      w += (size_t)EE * sizeof(int4);

    stats1_kernel<<<256, 256, 0, stream>>>(ea, partd);
    stats2_kernel<<<1, 256, 0, stream>>>(partd, stats);
    hipMemsetAsync(deg_t, 0, 2 * NN * sizeof(int), stream);
    edgepre_kernel<<<(EE + 255) / 256, 256, 0, stream>>>(
        ea, stats, eidx, deg_t, deg_s, epre4);
    cvtw_kernel<<<(192 * HIDC + 255) / 256, 256, 0, stream>>>(
        wi, wh, ew2, eb2, nw, wi_h, wh_h, w2b, nwb);
    initxn_kernel<<<(BN + 255) / 256, 256, 0, stream>>>(pm, xncur);
    hipMemsetAsync(hnA, 0, (size_t)32 * BN * sizeof(__half2), stream);
    scan_kernel<<<1, 1024, 0, stream>>>(deg_t, deg_s, off_t, off_s, cnt_t, cnt_s);
    fillperm_kernel<<<(EE + 255) / 256, 256, 0, stream>>>(
        eidx, epre4, cnt_t, cnt_s, eT, epreT);

    for (int t = 0; t < PREDC; t++) {
        const __half2* hnold = (t & 1) ? hnB : hnA;
        __half2*       hnnew = (t & 1) ? hnA : hnB;
        pre_kernel<<<(BN * 8 + 255) / 256, 256, 0, stream>>>(
            xncur, feat, t, xp, fb, ew1, wmean, wstd, preS, preT, wind2, out);
        edge_kernel<<<dim3(EE / 256, BB), 256, 0, stream>>>(
            eT, epreT, preS, preT, wind2, ew1, eb1, w2b, nwb, eb2, h3t, h3s);
        gather_kernel<<<(NN * 64 + 255) / 256, 256, 0, stream>>>(
            h3t, h3s, off_t, off_s, nb, xncur, xcagg);
        node_kernel<<<dim3(BN / 64, 4), 256, 0, stream>>>(
            xcagg, feat, t, wi_h, wh_h, bi, bh, fw, hnold, hnnew, xp);
    }
    finalout_kernel<<<(BN + 255) / 256, 256, 0, stream>>>(xp, fb, out);
}